// Round 1
// baseline (158.311 us; speedup 1.0000x reference)
//
#include <hip/hip_runtime.h>

// ---------- types ----------
using bh8    = __attribute__((ext_vector_type(8)))  short;          // 8 bf16 (4 VGPR)
using f32x4v = __attribute__((ext_vector_type(4)))  float;
using f32x16 = __attribute__((ext_vector_type(16))) float;
using u32x4  = __attribute__((ext_vector_type(4)))  unsigned int;
using us4    = __attribute__((ext_vector_type(4)))  unsigned short;

#define AS1 __attribute__((address_space(1)))
#define AS3 __attribute__((address_space(3)))

#define B_  2
#define S_  2048
#define D_  1024
#define H_  16
#define HD_ 64

__device__ __forceinline__ unsigned short f2bf(float f) {
  unsigned u = __builtin_bit_cast(unsigned, f);
  return (unsigned short)((u + 0x7fffu + ((u >> 16) & 1u)) >> 16);   // RNE
}
__device__ __forceinline__ int swz8(int r) { return (r ^ (r >> 3)) & 7; }

// ---------- f32 -> bf16 convert ----------
__global__ __launch_bounds__(256) void cvt_f32_bf16(const float* __restrict__ in,
                                                    unsigned short* __restrict__ out, int n4) {
  int i = blockIdx.x * 256 + threadIdx.x;
  if (i >= n4) return;
  f32x4v v = reinterpret_cast<const f32x4v*>(in)[i];
  us4 o;
  o[0] = f2bf(v[0]); o[1] = f2bf(v[1]); o[2] = f2bf(v[2]); o[3] = f2bf(v[3]);
  reinterpret_cast<us4*>(out)[i] = o;
}

// ---------- GEMM: C[m,e] = sum_k A[m,k]*B[e,k] (+bias) ----------
// MODE 0: scatter bf16 into Q/K/V [B*H][S][64] (+qkv bias)
// MODE 1: f32 out C[m*N+e] (+bias)
template <int MODE>
__global__ __launch_bounds__(256) void gemm_bt(const unsigned short* __restrict__ A,
                                               const unsigned short* __restrict__ Bw,
                                               const float* __restrict__ bias,
                                               float* __restrict__ Cf,
                                               unsigned short* __restrict__ Qo,
                                               unsigned short* __restrict__ Ko,
                                               unsigned short* __restrict__ Vo,
                                               int M, int N, int K) {
  __shared__ __align__(16) short As[128 * 64];   // [row][64] rows=128B, XOR-swizzled slots
  __shared__ __align__(16) short Bs[128 * 64];
  const int tid = threadIdx.x;
  const int w = tid >> 6, l = tid & 63;
  const int lr = l & 15, lg = l >> 4;
  const int m0 = blockIdx.x * 128, n0 = blockIdx.y * 128;
  const int wm = (w >> 1) * 64, wn = (w & 1) * 64;

  f32x4v acc[4][4];
#pragma unroll
  for (int a = 0; a < 4; a++)
#pragma unroll
    for (int b = 0; b < 4; b++)
#pragma unroll
      for (int r = 0; r < 4; r++) acc[a][b][r] = 0.f;

#pragma unroll 1
  for (int k0 = 0; k0 < K; k0 += 64) {
    __syncthreads();
    // stage A,B tiles: 16KB each = 4 issues x 256 thr x 16B. linear LDS dest,
    // inverse-swizzled global source (T2 / m173 pattern).
#pragma unroll
    for (int n = 0; n < 4; n++) {
      int idx = n * 256 + tid;
      int row = idx >> 3, p = idx & 7;
      int c = p ^ swz8(row);
      const unsigned short* srcA = A + (size_t)(m0 + row) * K + k0 + c * 8;
      const unsigned short* srcB = Bw + (size_t)(n0 + row) * K + k0 + c * 8;
      __builtin_amdgcn_global_load_lds((const AS1 void*)srcA,
          (AS3 void*)((char*)As + (n * 256 + w * 64) * 16), 16, 0, 0);
      __builtin_amdgcn_global_load_lds((const AS1 void*)srcB,
          (AS3 void*)((char*)Bs + (n * 256 + w * 64) * 16), 16, 0, 0);
    }
    __syncthreads();
#pragma unroll
    for (int kk = 0; kk < 2; kk++) {
      bh8 af[4], bf[4];
#pragma unroll
      for (int mi = 0; mi < 4; mi++) {
        int row = wm + mi * 16 + lr;
        int slot = (4 * kk + lg) ^ swz8(row);
        af[mi] = *(const bh8*)((const char*)As + row * 128 + slot * 16);
      }
#pragma unroll
      for (int ni = 0; ni < 4; ni++) {
        int row = wn + ni * 16 + lr;
        int slot = (4 * kk + lg) ^ swz8(row);
        bf[ni] = *(const bh8*)((const char*)Bs + row * 128 + slot * 16);
      }
#pragma unroll
      for (int mi = 0; mi < 4; mi++)
#pragma unroll
        for (int ni = 0; ni < 4; ni++)
          acc[mi][ni] = __builtin_amdgcn_mfma_f32_16x16x32_bf16(af[mi], bf[ni], acc[mi][ni], 0, 0, 0);
    }
  }

  // epilogue. D layout (16x16): col=e=lane&15, row=m=(lane>>4)*4+r  [m89]
  if (MODE == 1) {
#pragma unroll
    for (int ni = 0; ni < 4; ni++) {
      int e = n0 + wn + ni * 16 + lr;
      float bv = bias[e];
#pragma unroll
      for (int mi = 0; mi < 4; mi++) {
        int mbase = m0 + wm + mi * 16 + lg * 4;
#pragma unroll
        for (int r = 0; r < 4; r++)
          Cf[(size_t)(mbase + r) * N + e] = acc[mi][ni][r] + bv;
      }
    }
  } else {
#pragma unroll
    for (int ni = 0; ni < 4; ni++) {
      int e = n0 + wn + ni * 16 + lr;
      int hh = e / 192;
      int rr = e - hh * 192;
      int tsel = rr >> 6, d = rr & 63;
      float bv = bias[e];
      unsigned short* dst = (tsel == 0) ? Qo : (tsel == 1) ? Ko : Vo;
#pragma unroll
      for (int mi = 0; mi < 4; mi++) {
        int mbase = m0 + wm + mi * 16 + lg * 4;
#pragma unroll
        for (int r = 0; r < 4; r++) {
          int m = mbase + r;
          int b = m >> 11, s = m & 2047;
          dst[(((size_t)(b * H_ + hh)) * S_ + s) * HD_ + d] = f2bf(acc[mi][ni][r] + bv);
        }
      }
    }
  }
}

// ---------- fused attention ----------
// grid (S/128, B*H), 256 thr = 4 waves, wave owns 32 q-rows.
// swapped scores: S^T = mfma(K_frag, Q_frag) -> lane holds P-row slice for q = lane&31.
// no max-subtraction: exponent = 0.025*score bounded (~|1.5|).
__global__ __launch_bounds__(256) void attn_fwd(const unsigned short* __restrict__ Qt,
                                                const unsigned short* __restrict__ Kt,
                                                const unsigned short* __restrict__ Vg,
                                                unsigned short* __restrict__ vals) {
  __shared__ __align__(16) short Ks[64 * 64];   // [t][d] swizzled, 8KB
  __shared__ __align__(16) short Vs[64 * 64];   // [d][t] transposed+swizzled, 8KB
  __shared__ __align__(16) float Lbuf[4][32];
  const int tid = threadIdx.x, w = tid >> 6, l = tid & 63;
  const int lq = l & 31, h = l >> 5;
  const int bh = blockIdx.y;
  const int q0 = blockIdx.x * 128 + w * 32;
  const size_t base = (size_t)bh * S_ * HD_;
  const unsigned short* Qp = Qt + base;
  const unsigned short* Kp = Kt + base;
  const unsigned short* Vp = Vg + base;
  const float C2 = 0.0360673760222241f;  // 0.2/sqrt(64) * log2(e)

  bh8 qf[4];  // B-frags: col=q=lane&31, k=d=(lane>>5)*8+j, 16 per kf
#pragma unroll
  for (int kf = 0; kf < 4; kf++)
    qf[kf] = *(const bh8*)(Qp + (size_t)(q0 + lq) * HD_ + kf * 16 + h * 8);

  f32x16 O[2];
#pragma unroll
  for (int ni = 0; ni < 2; ni++)
#pragma unroll
    for (int r = 0; r < 16; r++) O[ni][r] = 0.f;
  float Lp = 0.f;

#pragma unroll 1
  for (int t0 = 0; t0 < S_; t0 += 64) {
    __syncthreads();
    // stage K [64][64] via global_load_lds, inverse-swizzled source
#pragma unroll
    for (int n = 0; n < 2; n++) {
      int idx = n * 256 + tid;
      int row = idx >> 3, p = idx & 7;
      int c = p ^ swz8(row);
      const unsigned short* src = Kp + (size_t)(t0 + row) * HD_ + c * 8;
      __builtin_amdgcn_global_load_lds((const AS1 void*)src,
          (AS3 void*)((char*)Ks + (n * 256 + w * 64) * 16), 16, 0, 0);
    }
    // stage V transposed: Vs[d][t], byte = d*128 + ((2t) ^ (swz8(d)<<4))
#pragma unroll
    for (int pp = 0; pp < 2; pp++) {
      int t = (tid >> 3) + pp * 32;
      int d0 = (tid & 7) * 8;
      bh8 vv = *(const bh8*)(Vp + (size_t)(t0 + t) * HD_ + d0);
#pragma unroll
      for (int j = 0; j < 8; j++) {
        int d = d0 + j;
        int off = d * 128 + ((2 * t) ^ (swz8(d) << 4));
        *(short*)((char*)Vs + off) = vv[j];
      }
    }
    __syncthreads();

#pragma unroll
    for (int tsb = 0; tsb < 2; tsb++) {
      const int ts = tsb * 32;
      f32x16 sc;
#pragma unroll
      for (int r = 0; r < 16; r++) sc[r] = 0.f;
#pragma unroll
      for (int kf = 0; kf < 4; kf++) {
        int row = ts + lq;
        int slot = (2 * kf + h) ^ swz8(row);
        bh8 kfr = *(const bh8*)((const char*)Ks + row * 128 + slot * 16);
        sc = __builtin_amdgcn_mfma_f32_32x32x16_bf16(kfr, qf[kf], sc, 0, 0, 0);
      }
      // lane holds P[q=lq][t' = (r&3)+8*(r>>2)+4h] (within this 32-t subtile)
      float pv[16];
      float ls = 0.f;
#pragma unroll
      for (int r = 0; r < 16; r++) { pv[r] = exp2f(sc[r] * C2); ls += pv[r]; }
      Lp += ls;
      // pack to bf16 pairs: w0[p] -> t' = 8p+4h+{0,1}, w1[p] -> +{2,3}
      unsigned w0[4], w1[4];
#pragma unroll
      for (int g = 0; g < 4; g++) {
        w0[g] = (unsigned)f2bf(pv[4 * g]) | ((unsigned)f2bf(pv[4 * g + 1]) << 16);
        w1[g] = (unsigned)f2bf(pv[4 * g + 2]) | ((unsigned)f2bf(pv[4 * g + 3]) << 16);
      }
      // rebuild PV A-frags (k = t = 8h+j) via half-swap (T12 structure)
#pragma unroll
      for (int c = 0; c < 2; c++) {
        unsigned s0 = (unsigned)__shfl_xor((int)w0[2 * c], 32);
        unsigned s1 = (unsigned)__shfl_xor((int)w0[2 * c + 1], 32);
        unsigned s2 = (unsigned)__shfl_xor((int)w1[2 * c], 32);
        unsigned s3 = (unsigned)__shfl_xor((int)w1[2 * c + 1], 32);
        u32x4 uu;
        uu[0] = h ? s1 : w0[2 * c];
        uu[1] = h ? s3 : w1[2 * c];
        uu[2] = h ? w0[2 * c + 1] : s0;
        uu[3] = h ? w1[2 * c + 1] : s2;
        bh8 pa = __builtin_bit_cast(bh8, uu);
#pragma unroll
        for (int ni = 0; ni < 2; ni++) {
          int d = ni * 32 + lq;
          int slot = ((ts >> 3) + 2 * c + h) ^ swz8(d);
          bh8 vf = *(const bh8*)((const char*)Vs + d * 128 + slot * 16);
          O[ni] = __builtin_amdgcn_mfma_f32_32x32x16_bf16(pa, vf, O[ni], 0, 0, 0);
        }
      }
    }
  }

  // denominators: lane's partial covers its 16 t' per tile for q=lq; partner lane q+32 has rest
  float Lt = Lp + __shfl_xor(Lp, 32);
  __syncthreads();
  if (l < 32) Lbuf[w][l] = Lt;
  __syncthreads();
  f32x4v Lq[4];
#pragma unroll
  for (int rq = 0; rq < 4; rq++) Lq[rq] = *(const f32x4v*)&Lbuf[w][4 * h + 8 * rq];

  const int b = bh >> 4, hh = bh & 15;
#pragma unroll
  for (int ni = 0; ni < 2; ni++) {
    int d = ni * 32 + lq;
#pragma unroll
    for (int r = 0; r < 16; r++) {
      float vvv = O[ni][r] / Lq[r >> 2][r & 3];
      int qg = q0 + 4 * h + 8 * (r >> 2) + (r & 3);
      vals[((size_t)(b * S_ + qg)) * D_ + hh * HD_ + d] = f2bf(vvv);
    }
  }
}

// ---------- launch ----------
extern "C" void kernel_launch(void* const* d_in, const int* in_sizes, int n_in,
                              void* d_out, int out_size, void* d_ws, size_t ws_size,
                              hipStream_t stream) {
  const float* x     = (const float*)d_in[0];
  const float* qkv_w = (const float*)d_in[1];
  const float* qkv_b = (const float*)d_in[2];
  const float* out_w = (const float*)d_in[3];
  const float* out_b = (const float*)d_in[4];
  float* out = (float*)d_out;

  unsigned short* xb  = (unsigned short*)d_ws;                 // 8 MB  x bf16 [4096][1024]
  unsigned short* qwb = xb  + (size_t)4096 * 1024;             // 6 MB  qkv_w bf16 [3072][1024]
  unsigned short* owb = qwb + (size_t)3072 * 1024;             // 2 MB  out_w bf16 [1024][1024]
  unsigned short* Qb  = owb + (size_t)1024 * 1024;             // 8 MB  Q [32][2048][64]
  unsigned short* Kb  = Qb  + (size_t)32 * 2048 * 64;          // 8 MB
  unsigned short* Vb  = Kb  + (size_t)32 * 2048 * 64;          // 8 MB
  unsigned short* vb  = Vb  + (size_t)32 * 2048 * 64;          // 8 MB  vals bf16 [4096][1024]

  cvt_f32_bf16<<<(4096 * 1024 / 4) / 256, 256, 0, stream>>>(x, xb, 4096 * 1024 / 4);
  cvt_f32_bf16<<<(3072 * 1024 / 4) / 256, 256, 0, stream>>>(qkv_w, qwb, 3072 * 1024 / 4);
  cvt_f32_bf16<<<(1024 * 1024 / 4) / 256, 256, 0, stream>>>(out_w, owb, 1024 * 1024 / 4);

  gemm_bt<0><<<dim3(32, 24), 256, 0, stream>>>(xb, qwb, qkv_b, nullptr, Qb, Kb, Vb,
                                               4096, 3072, 1024);
  attn_fwd<<<dim3(16, 32), 256, 0, stream>>>(Qb, Kb, Vb, vb);
  gemm_bt<1><<<dim3(32, 8), 256, 0, stream>>>(vb, owb, out_b, out, nullptr, nullptr, nullptr,
                                              4096, 1024, 1024);
}

// Round 2
// 127.447 us; speedup vs baseline: 1.2422x; 1.2422x over previous
//
#include <hip/hip_runtime.h>

// ---------- types ----------
using bh8    = __attribute__((ext_vector_type(8)))  short;          // 8 bf16 (4 VGPR)
using f32x4v = __attribute__((ext_vector_type(4)))  float;
using f32x16 = __attribute__((ext_vector_type(16))) float;
using u32x4  = __attribute__((ext_vector_type(4)))  unsigned int;
using us4    = __attribute__((ext_vector_type(4)))  unsigned short;

#define AS1 __attribute__((address_space(1)))
#define AS3 __attribute__((address_space(3)))

#define B_  2
#define S_  2048
#define D_  1024
#define H_  16
#define HD_ 64
#define C2A 0.0360673760222241f   // 0.2/sqrt(64) * log2(e), folded into Q

__device__ __forceinline__ unsigned short f2bf(float f) {
  unsigned u = __builtin_bit_cast(unsigned, f);
  return (unsigned short)((u + 0x7fffu + ((u >> 16) & 1u)) >> 16);   // RNE
}
__device__ __forceinline__ int swz8(int r) { return (r ^ (r >> 3)) & 7; }

// ---------- f32 -> bf16 convert ----------
__global__ __launch_bounds__(256) void cvt_f32_bf16(const float* __restrict__ in,
                                                    unsigned short* __restrict__ out, int n4) {
  int i = blockIdx.x * 256 + threadIdx.x;
  if (i >= n4) return;
  f32x4v v = reinterpret_cast<const f32x4v*>(in)[i];
  us4 o;
  o[0] = f2bf(v[0]); o[1] = f2bf(v[1]); o[2] = f2bf(v[2]); o[3] = f2bf(v[3]);
  reinterpret_cast<us4*>(out)[i] = o;
}

// ---------- GEMM: C[m,e] = sum_k A[m,k]*B[e,k] (+bias) ----------
// MODE 0: scatter bf16: Q (scaled by C2A) [bh][s][64], K [bh][s][64], V^T [bh][d][S]
// MODE 1: f32 out C[m*N+e] (+bias)
template <int MODE>
__global__ __launch_bounds__(256) void gemm_bt(const unsigned short* __restrict__ A,
                                               const unsigned short* __restrict__ Bw,
                                               const float* __restrict__ bias,
                                               float* __restrict__ Cf,
                                               unsigned short* __restrict__ Qo,
                                               unsigned short* __restrict__ Ko,
                                               unsigned short* __restrict__ Vo,
                                               int M, int N, int K) {
  __shared__ __align__(16) short As[128 * 64];
  __shared__ __align__(16) short Bs[128 * 64];
  const int tid = threadIdx.x;
  const int w = tid >> 6, l = tid & 63;
  const int lr = l & 15, lg = l >> 4;
  const int m0 = blockIdx.x * 128, n0 = blockIdx.y * 128;
  const int wm = (w >> 1) * 64, wn = (w & 1) * 64;

  f32x4v acc[4][4];
#pragma unroll
  for (int a = 0; a < 4; a++)
#pragma unroll
    for (int b = 0; b < 4; b++)
#pragma unroll
      for (int r = 0; r < 4; r++) acc[a][b][r] = 0.f;

#pragma unroll 1
  for (int k0 = 0; k0 < K; k0 += 64) {
    __syncthreads();
#pragma unroll
    for (int n = 0; n < 4; n++) {
      int idx = n * 256 + tid;
      int row = idx >> 3, p = idx & 7;
      int c = p ^ swz8(row);
      const unsigned short* srcA = A + (size_t)(m0 + row) * K + k0 + c * 8;
      const unsigned short* srcB = Bw + (size_t)(n0 + row) * K + k0 + c * 8;
      __builtin_amdgcn_global_load_lds((const AS1 void*)srcA,
          (AS3 void*)((char*)As + (n * 256 + w * 64) * 16), 16, 0, 0);
      __builtin_amdgcn_global_load_lds((const AS1 void*)srcB,
          (AS3 void*)((char*)Bs + (n * 256 + w * 64) * 16), 16, 0, 0);
    }
    __syncthreads();
#pragma unroll
    for (int kk = 0; kk < 2; kk++) {
      bh8 af[4], bf[4];
#pragma unroll
      for (int mi = 0; mi < 4; mi++) {
        int row = wm + mi * 16 + lr;
        int slot = (4 * kk + lg) ^ swz8(row);
        af[mi] = *(const bh8*)((const char*)As + row * 128 + slot * 16);
      }
#pragma unroll
      for (int ni = 0; ni < 4; ni++) {
        int row = wn + ni * 16 + lr;
        int slot = (4 * kk + lg) ^ swz8(row);
        bf[ni] = *(const bh8*)((const char*)Bs + row * 128 + slot * 16);
      }
#pragma unroll
      for (int mi = 0; mi < 4; mi++)
#pragma unroll
        for (int ni = 0; ni < 4; ni++)
          acc[mi][ni] = __builtin_amdgcn_mfma_f32_16x16x32_bf16(af[mi], bf[ni], acc[mi][ni], 0, 0, 0);
    }
  }

  // D layout (16x16): col=e=lane&15, row=m=(lane>>4)*4+r  [m89]
  if (MODE == 1) {
#pragma unroll
    for (int ni = 0; ni < 4; ni++) {
      int e = n0 + wn + ni * 16 + lr;
      float bv = bias[e];
#pragma unroll
      for (int mi = 0; mi < 4; mi++) {
        int mbase = m0 + wm + mi * 16 + lg * 4;
#pragma unroll
        for (int r = 0; r < 4; r++)
          Cf[(size_t)(mbase + r) * N + e] = acc[mi][ni][r] + bv;
      }
    }
  } else {
#pragma unroll
    for (int ni = 0; ni < 4; ni++) {
      int e = n0 + wn + ni * 16 + lr;
      int hh = e / 192;
      int rr = e - hh * 192;
      int tsel = rr >> 6, d = rr & 63;
      float bv = bias[e];
#pragma unroll
      for (int mi = 0; mi < 4; mi++) {
        int mbase = m0 + wm + mi * 16 + lg * 4;
#pragma unroll
        for (int r = 0; r < 4; r++) {
          int m = mbase + r;
          int b = m >> 11, s = m & 2047;
          float val = acc[mi][ni][r] + bv;
          size_t bh = (size_t)(b * H_ + hh);
          if (tsel == 0)      Qo[(bh * S_ + s) * HD_ + d] = f2bf(val * C2A);
          else if (tsel == 1) Ko[(bh * S_ + s) * HD_ + d] = f2bf(val);
          else                Vo[(bh * HD_ + d) * S_ + s] = f2bf(val);   // V^T
        }
      }
    }
  }
}

// ---------- fused attention ----------
// grid 512 (XCD-swizzled), 256 thr = 4 waves, wave owns 32 q-rows.
// swapped scores: S^T = mfma(K_frag, Q_frag); Q pre-scaled -> exp2 direct.
// K [t][d] and V^T [d][t] both staged via global_load_lds, double-buffered.
__global__ __launch_bounds__(256) void attn_fwd(const unsigned short* __restrict__ Qt,
                                                const unsigned short* __restrict__ Kt,
                                                const unsigned short* __restrict__ VT,
                                                unsigned short* __restrict__ vals) {
  __shared__ __align__(16) short Ks[2 * 64 * 64];   // 16KB double-buffered
  __shared__ __align__(16) short Vs[2 * 64 * 64];   // 16KB
  __shared__ __align__(16) float Lbuf[4][32];
  const int tid = threadIdx.x, w = tid >> 6, l = tid & 63;
  const int lq = l & 31, h = l >> 5;
  // XCD swizzle: all 16 q-blocks of a (b,h) land on one XCD (same lin%8)
  const int lin = blockIdx.x;
  const int uu_ = lin >> 3;
  const int bh = (lin & 7) + 8 * (uu_ & 3);
  const int q0 = (uu_ >> 2) * 128 + w * 32;
  const unsigned short* Qp = Qt + (size_t)bh * S_ * HD_;
  const unsigned short* Kp = Kt + (size_t)bh * S_ * HD_;
  const unsigned short* Vp = VT + (size_t)bh * HD_ * S_;

  bh8 qf[4];  // B-frags: col=q=lane&31, k=d=(lane>>5)*8+j
#pragma unroll
  for (int kf = 0; kf < 4; kf++)
    qf[kf] = *(const bh8*)(Qp + (size_t)(q0 + lq) * HD_ + kf * 16 + h * 8);

  f32x16 O[2];
#pragma unroll
  for (int ni = 0; ni < 2; ni++)
#pragma unroll
    for (int r = 0; r < 16; r++) O[ni][r] = 0.f;
  float Lp = 0.f;

  // per-thread staging addresses (fixed; advance by tile)
  const int row0 = tid >> 3,        c0 = (tid & 7) ^ swz8(row0);
  const int row1 = (256 + tid) >> 3, c1 = (tid & 7) ^ swz8(row1);
  const unsigned short* kp0 = Kp + row0 * HD_ + c0 * 8;
  const unsigned short* kp1 = Kp + row1 * HD_ + c1 * 8;
  const unsigned short* vp0 = Vp + (size_t)row0 * S_ + c0 * 8;
  const unsigned short* vp1 = Vp + (size_t)row1 * S_ + c1 * 8;
  char* dK = (char*)Ks + w * 64 * 16;
  char* dV = (char*)Vs + w * 64 * 16;

  auto stage = [&](int t, int buf) {
    __builtin_amdgcn_global_load_lds((const AS1 void*)(kp0 + (size_t)t * 4096),
                                     (AS3 void*)(dK + buf * 8192), 16, 0, 0);
    __builtin_amdgcn_global_load_lds((const AS1 void*)(kp1 + (size_t)t * 4096),
                                     (AS3 void*)(dK + buf * 8192 + 4096), 16, 0, 0);
    __builtin_amdgcn_global_load_lds((const AS1 void*)(vp0 + (size_t)t * 64),
                                     (AS3 void*)(dV + buf * 8192), 16, 0, 0);
    __builtin_amdgcn_global_load_lds((const AS1 void*)(vp1 + (size_t)t * 64),
                                     (AS3 void*)(dV + buf * 8192 + 4096), 16, 0, 0);
  };

  stage(0, 0);
#pragma unroll 1
  for (int i = 0; i < 32; i++) {
    const int cur = i & 1;
    asm volatile("s_waitcnt vmcnt(0)" ::: "memory");   // my tile-i staging done
    __builtin_amdgcn_s_barrier();                      // everyone staged; prev-buf readers done
    if (i < 31) stage(i + 1, cur ^ 1);                 // prefetch flies under compute
    const char* Kc = (const char*)Ks + cur * 8192;
    const char* Vc = (const char*)Vs + cur * 8192;
#pragma unroll
    for (int tsb = 0; tsb < 2; tsb++) {
      const int ts = tsb * 32;
      f32x16 sc;
#pragma unroll
      for (int r = 0; r < 16; r++) sc[r] = 0.f;
      __builtin_amdgcn_s_setprio(1);
#pragma unroll
      for (int kf = 0; kf < 4; kf++) {
        int row = ts + lq;
        int slot = (2 * kf + h) ^ swz8(row);
        bh8 kfr = *(const bh8*)(Kc + row * 128 + slot * 16);
        sc = __builtin_amdgcn_mfma_f32_32x32x16_bf16(kfr, qf[kf], sc, 0, 0, 0);
      }
      __builtin_amdgcn_s_setprio(0);
      // lane holds P[q=lq][t' = (r&3)+8*(r>>2)+4h]; exponent already scaled
      float pv[16];
#pragma unroll
      for (int r = 0; r < 16; r++)
        asm("v_exp_f32 %0, %1" : "=v"(pv[r]) : "v"(sc[r]));
      // tree-sum of 16
      float s8[8], s4[4], s2[2];
#pragma unroll
      for (int g = 0; g < 8; g++) s8[g] = pv[2 * g] + pv[2 * g + 1];
#pragma unroll
      for (int g = 0; g < 4; g++) s4[g] = s8[2 * g] + s8[2 * g + 1];
      s2[0] = s4[0] + s4[1]; s2[1] = s4[2] + s4[3];
      Lp += s2[0] + s2[1];
      // pack to bf16 pairs: w0[g] -> t' = 8g+4h+{0,1}, w1[g] -> +{2,3}
      unsigned w0[4], w1[4];
#pragma unroll
      for (int g = 0; g < 4; g++) {
        asm("v_cvt_pk_bf16_f32 %0, %1, %2" : "=v"(w0[g]) : "v"(pv[4 * g]), "v"(pv[4 * g + 1]));
        asm("v_cvt_pk_bf16_f32 %0, %1, %2" : "=v"(w1[g]) : "v"(pv[4 * g + 2]), "v"(pv[4 * g + 3]));
      }
      // rebuild PV A-frags (k = t = 8h+j) via permlane32_swap (T12)
#pragma unroll
      for (int c = 0; c < 2; c++) {
        unsigned a0 = w0[2 * c], b0 = w0[2 * c + 1];
        unsigned a1 = w1[2 * c], b1 = w1[2 * c + 1];
        asm("v_permlane32_swap_b32 %0, %1" : "+v"(a0), "+v"(b0));
        asm("v_permlane32_swap_b32 %0, %1" : "+v"(a1), "+v"(b1));
        u32x4 up; up[0] = a0; up[1] = a1; up[2] = b0; up[3] = b1;
        bh8 pa = __builtin_bit_cast(bh8, up);
        __builtin_amdgcn_s_setprio(1);
#pragma unroll
        for (int ni = 0; ni < 2; ni++) {
          int d = ni * 32 + lq;
          int slot = (4 * tsb + 2 * c + h) ^ swz8(d);
          bh8 vf = *(const bh8*)(Vc + d * 128 + slot * 16);
          O[ni] = __builtin_amdgcn_mfma_f32_32x32x16_bf16(pa, vf, O[ni], 0, 0, 0);
        }
        __builtin_amdgcn_s_setprio(0);
      }
    }
  }

  // denominators: partner lane (q+32 half) holds the other 16 t' per subtile
  float Lt = Lp + __shfl_xor(Lp, 32);
  if (l < 32) Lbuf[w][l] = Lt;        // intra-wave LDS: program order suffices
  f32x4v Lq[4];
#pragma unroll
  for (int rq = 0; rq < 4; rq++) Lq[rq] = *(const f32x4v*)&Lbuf[w][4 * h + 8 * rq];
  float rl[16];
#pragma unroll
  for (int rq = 0; rq < 4; rq++)
#pragma unroll
    for (int j = 0; j < 4; j++) rl[4 * rq + j] = __builtin_amdgcn_rcpf(Lq[rq][j]);

  const int b = bh >> 4, hh = bh & 15;
#pragma unroll
  for (int ni = 0; ni < 2; ni++) {
    int d = ni * 32 + lq;
#pragma unroll
    for (int r = 0; r < 16; r++) {
      float vvv = O[ni][r] * rl[4 * (r >> 2) + (r & 3)];
      int qg = q0 + 4 * h + 8 * (r >> 2) + (r & 3);
      vals[((size_t)(b * S_ + qg)) * D_ + hh * HD_ + d] = f2bf(vvv);
    }
  }
}

// ---------- launch ----------
extern "C" void kernel_launch(void* const* d_in, const int* in_sizes, int n_in,
                              void* d_out, int out_size, void* d_ws, size_t ws_size,
                              hipStream_t stream) {
  const float* x     = (const float*)d_in[0];
  const float* qkv_w = (const float*)d_in[1];
  const float* qkv_b = (const float*)d_in[2];
  const float* out_w = (const float*)d_in[3];
  const float* out_b = (const float*)d_in[4];
  float* out = (float*)d_out;

  unsigned short* xb  = (unsigned short*)d_ws;                 // 8 MB  x bf16 [4096][1024]
  unsigned short* qwb = xb  + (size_t)4096 * 1024;             // 6 MB  qkv_w bf16
  unsigned short* owb = qwb + (size_t)3072 * 1024;             // 2 MB  out_w bf16
  unsigned short* Qb  = owb + (size_t)1024 * 1024;             // 8 MB  Q*C2 [32][2048][64]
  unsigned short* Kb  = Qb  + (size_t)32 * 2048 * 64;          // 8 MB  K [32][2048][64]
  unsigned short* Vb  = Kb  + (size_t)32 * 2048 * 64;          // 8 MB  V^T [32][64][2048]
  unsigned short* vb  = Vb  + (size_t)32 * 2048 * 64;          // 8 MB  vals bf16

  cvt_f32_bf16<<<(4096 * 1024 / 4) / 256, 256, 0, stream>>>(x, xb, 4096 * 1024 / 4);
  cvt_f32_bf16<<<(3072 * 1024 / 4) / 256, 256, 0, stream>>>(qkv_w, qwb, 3072 * 1024 / 4);
  cvt_f32_bf16<<<(1024 * 1024 / 4) / 256, 256, 0, stream>>>(out_w, owb, 1024 * 1024 / 4);

  gemm_bt<0><<<dim3(32, 24), 256, 0, stream>>>(xb, qwb, qkv_b, nullptr, Qb, Kb, Vb,
                                               4096, 3072, 1024);
  attn_fwd<<<512, 256, 0, stream>>>(Qb, Kb, Vb, vb);
  gemm_bt<1><<<dim3(32, 8), 256, 0, stream>>>(vb, owb, out_b, out, nullptr, nullptr, nullptr,
                                              4096, 1024, 1024);
}

// Round 5
// 123.182 us; speedup vs baseline: 1.2852x; 1.0346x over previous
//
#include <hip/hip_runtime.h>

// ---------- types ----------
using bh8    = __attribute__((ext_vector_type(8)))  short;          // 8 bf16 (4 VGPR)
using f32x4v = __attribute__((ext_vector_type(4)))  float;
using f32x16 = __attribute__((ext_vector_type(16))) float;
using u32x4  = __attribute__((ext_vector_type(4)))  unsigned int;
using us4    = __attribute__((ext_vector_type(4)))  unsigned short;

#define AS1 __attribute__((address_space(1)))
#define AS3 __attribute__((address_space(3)))

#define B_  2
#define S_  2048
#define D_  1024
#define H_  16
#define HD_ 64
#define C2A 0.0360673760222241f   // 0.2/sqrt(64) * log2(e), folded into Q

__device__ __forceinline__ unsigned short f2bf(float f) {
  unsigned u = __builtin_bit_cast(unsigned, f);
  return (unsigned short)((u + 0x7fffu + ((u >> 16) & 1u)) >> 16);   // RNE
}
__device__ __forceinline__ int swz8(int r) { return (r ^ (r >> 3)) & 7; }

// ---------- fused f32 -> bf16 convert (x, qkv_w, out_w in one launch) ----------
__global__ __launch_bounds__(256) void cvt_all(const float* __restrict__ x,
                                               const float* __restrict__ qw,
                                               const float* __restrict__ ow,
                                               unsigned short* __restrict__ xb,
                                               unsigned short* __restrict__ qwb,
                                               unsigned short* __restrict__ owb) {
  int i = blockIdx.x * 256 + threadIdx.x;     // vec4 index over 8M floats
  const float* src; unsigned short* dst; int off;
  if (i < 1048576)      { src = x;  dst = xb;  off = i; }
  else if (i < 1835008) { src = qw; dst = qwb; off = i - 1048576; }
  else                  { src = ow; dst = owb; off = i - 1835008; }
  f32x4v v = reinterpret_cast<const f32x4v*>(src)[off];
  us4 o;
  o[0] = f2bf(v[0]); o[1] = f2bf(v[1]); o[2] = f2bf(v[2]); o[3] = f2bf(v[3]);
  reinterpret_cast<us4*>(dst)[off] = o;
}

// ---------- GEMM: C[m,e] = sum_k A[m,k]*B[e,k] (+bias) ----------
// MODE 0: scatter bf16: Q (scaled by C2A) [bh][s][64], K [bh][s][64], V^T [bh][d][S]
// MODE 1: f32 out C[m*N+e] (+bias)
template <int MODE>
__global__ __launch_bounds__(256) void gemm_bt(const unsigned short* __restrict__ A,
                                               const unsigned short* __restrict__ Bw,
                                               const float* __restrict__ bias,
                                               float* __restrict__ Cf,
                                               unsigned short* __restrict__ Qo,
                                               unsigned short* __restrict__ Ko,
                                               unsigned short* __restrict__ Vo,
                                               int M, int N, int K) {
  __shared__ __align__(16) short As[128 * 64];
  __shared__ __align__(16) short Bs[128 * 64];
  const int tid = threadIdx.x;
  const int w = tid >> 6, l = tid & 63;
  const int lr = l & 15, lg = l >> 4;
  const int m0 = blockIdx.x * 128, n0 = blockIdx.y * 128;
  const int wm = (w >> 1) * 64, wn = (w & 1) * 64;

  f32x4v acc[4][4];
#pragma unroll
  for (int a = 0; a < 4; a++)
#pragma unroll
    for (int b = 0; b < 4; b++)
#pragma unroll
      for (int r = 0; r < 4; r++) acc[a][b][r] = 0.f;

#pragma unroll 1
  for (int k0 = 0; k0 < K; k0 += 64) {
    __syncthreads();
#pragma unroll
    for (int n = 0; n < 4; n++) {
      int idx = n * 256 + tid;
      int row = idx >> 3, p = idx & 7;
      int c = p ^ swz8(row);
      const unsigned short* srcA = A + (size_t)(m0 + row) * K + k0 + c * 8;
      const unsigned short* srcB = Bw + (size_t)(n0 + row) * K + k0 + c * 8;
      __builtin_amdgcn_global_load_lds((const AS1 void*)srcA,
          (AS3 void*)((char*)As + (n * 256 + w * 64) * 16), 16, 0, 0);
      __builtin_amdgcn_global_load_lds((const AS1 void*)srcB,
          (AS3 void*)((char*)Bs + (n * 256 + w * 64) * 16), 16, 0, 0);
    }
    __syncthreads();
#pragma unroll
    for (int kk = 0; kk < 2; kk++) {
      bh8 af[4], bf[4];
#pragma unroll
      for (int mi = 0; mi < 4; mi++) {
        int row = wm + mi * 16 + lr;
        int slot = (4 * kk + lg) ^ swz8(row);
        af[mi] = *(const bh8*)((const char*)As + row * 128 + slot * 16);
      }
#pragma unroll
      for (int ni = 0; ni < 4; ni++) {
        int row = wn + ni * 16 + lr;
        int slot = (4 * kk + lg) ^ swz8(row);
        bf[ni] = *(const bh8*)((const char*)Bs + row * 128 + slot * 16);
      }
#pragma unroll
      for (int mi = 0; mi < 4; mi++)
#pragma unroll
        for (int ni = 0; ni < 4; ni++)
          acc[mi][ni] = __builtin_amdgcn_mfma_f32_16x16x32_bf16(af[mi], bf[ni], acc[mi][ni], 0, 0, 0);
    }
  }

  // D layout (16x16): col=e=lane&15, row=m=(lane>>4)*4+r  [m89]
  if (MODE == 1) {
#pragma unroll
    for (int ni = 0; ni < 4; ni++) {
      int e = n0 + wn + ni * 16 + lr;
      float bv = bias[e];
#pragma unroll
      for (int mi = 0; mi < 4; mi++) {
        int mbase = m0 + wm + mi * 16 + lg * 4;
#pragma unroll
        for (int r = 0; r < 4; r++)
          Cf[(size_t)(mbase + r) * N + e] = acc[mi][ni][r] + bv;
      }
    }
  } else {
#pragma unroll
    for (int ni = 0; ni < 4; ni++) {
      int e = n0 + wn + ni * 16 + lr;
      int hh = e / 192;
      int rr = e - hh * 192;
      int tsel = rr >> 6, d = rr & 63;
      float bv = bias[e];
#pragma unroll
      for (int mi = 0; mi < 4; mi++) {
        int mbase = m0 + wm + mi * 16 + lg * 4;
#pragma unroll
        for (int r = 0; r < 4; r++) {
          int m = mbase + r;
          int b = m >> 11, s = m & 2047;
          float val = acc[mi][ni][r] + bv;
          size_t bh = (size_t)(b * H_ + hh);
          if (tsel == 0)      Qo[(bh * S_ + s) * HD_ + d] = f2bf(val * C2A);
          else if (tsel == 1) Ko[(bh * S_ + s) * HD_ + d] = f2bf(val);
          else                Vo[(bh * HD_ + d) * S_ + s] = f2bf(val);   // V^T
        }
      }
    }
  }
}

// ---------- fused attention (R2-verified template, byte-for-byte) ----------
// grid 512 (XCD-swizzled), 256 thr = 4 waves, wave owns 32 q-rows.
// swapped scores: S^T = mfma(K_frag, Q_frag); Q pre-scaled -> exp direct.
// K [t][d] and V^T [d][t] both staged via global_load_lds, double-buffered.
__global__ __launch_bounds__(256) void attn_fwd(const unsigned short* __restrict__ Qt,
                                                const unsigned short* __restrict__ Kt,
                                                const unsigned short* __restrict__ VT,
                                                unsigned short* __restrict__ vals) {
  __shared__ __align__(16) short Ks[2 * 64 * 64];   // 16KB double-buffered
  __shared__ __align__(16) short Vs[2 * 64 * 64];   // 16KB
  __shared__ __align__(16) float Lbuf[4][32];
  const int tid = threadIdx.x, w = tid >> 6, l = tid & 63;
  const int lq = l & 31, h = l >> 5;
  // XCD swizzle: all 16 q-blocks of a (b,h) land on one XCD (same lin%8)
  const int lin = blockIdx.x;
  const int uu_ = lin >> 3;
  const int bh = (lin & 7) + 8 * (uu_ & 3);
  const int q0 = (uu_ >> 2) * 128 + w * 32;
  const unsigned short* Qp = Qt + (size_t)bh * (S_ * HD_);
  const unsigned short* Kp = Kt + (size_t)bh * (S_ * HD_);
  const unsigned short* Vp = VT + (size_t)bh * (HD_ * S_);

  bh8 qf[4];  // B-frags: col=q=lane&31, k=d=(lane>>5)*8+j
#pragma unroll
  for (int kf = 0; kf < 4; kf++)
    qf[kf] = *(const bh8*)(Qp + (size_t)(q0 + lq) * HD_ + kf * 16 + h * 8);

  f32x16 O[2];
#pragma unroll
  for (int ni = 0; ni < 2; ni++)
#pragma unroll
    for (int r = 0; r < 16; r++) O[ni][r] = 0.f;
  float Lp = 0.f;

  // per-thread staging addresses (fixed; advance by tile)
  const int row0 = tid >> 3,        c0 = (tid & 7) ^ swz8(row0);
  const int row1 = (256 + tid) >> 3, c1 = (tid & 7) ^ swz8(row1);
  const unsigned short* kp0 = Kp + row0 * HD_ + c0 * 8;
  const unsigned short* kp1 = Kp + row1 * HD_ + c1 * 8;
  const unsigned short* vp0 = Vp + (size_t)row0 * S_ + c0 * 8;
  const unsigned short* vp1 = Vp + (size_t)row1 * S_ + c1 * 8;
  char* dK = (char*)Ks + w * 64 * 16;
  char* dV = (char*)Vs + w * 64 * 16;

  auto stage = [&](int t, int buf) {
    __builtin_amdgcn_global_load_lds((const AS1 void*)(kp0 + (size_t)t * 4096),
                                     (AS3 void*)(dK + buf * 8192), 16, 0, 0);
    __builtin_amdgcn_global_load_lds((const AS1 void*)(kp1 + (size_t)t * 4096),
                                     (AS3 void*)(dK + buf * 8192 + 4096), 16, 0, 0);
    __builtin_amdgcn_global_load_lds((const AS1 void*)(vp0 + (size_t)t * 64),
                                     (AS3 void*)(dV + buf * 8192), 16, 0, 0);
    __builtin_amdgcn_global_load_lds((const AS1 void*)(vp1 + (size_t)t * 64),
                                     (AS3 void*)(dV + buf * 8192 + 4096), 16, 0, 0);
  };

  stage(0, 0);
#pragma unroll 1
  for (int i = 0; i < 32; i++) {
    const int cur = i & 1;
    asm volatile("s_waitcnt vmcnt(0)" ::: "memory");   // my tile-i staging done
    __builtin_amdgcn_s_barrier();                      // everyone staged; prev-buf readers done
    if (i < 31) stage(i + 1, cur ^ 1);                 // prefetch flies under compute
    const char* Kc = (const char*)Ks + cur * 8192;
    const char* Vc = (const char*)Vs + cur * 8192;
#pragma unroll
    for (int tsb = 0; tsb < 2; tsb++) {
      const int ts = tsb * 32;
      f32x16 sc;
#pragma unroll
      for (int r = 0; r < 16; r++) sc[r] = 0.f;
      __builtin_amdgcn_s_setprio(1);
#pragma unroll
      for (int kf = 0; kf < 4; kf++) {
        int row = ts + lq;
        int slot = (2 * kf + h) ^ swz8(row);
        bh8 kfr = *(const bh8*)(Kc + row * 128 + slot * 16);
        sc = __builtin_amdgcn_mfma_f32_32x32x16_bf16(kfr, qf[kf], sc, 0, 0, 0);
      }
      __builtin_amdgcn_s_setprio(0);
      // lane holds P[q=lq][t' = (r&3)+8*(r>>2)+4h]; exponent already scaled
      float pv[16];
#pragma unroll
      for (int r = 0; r < 16; r++)
        asm("v_exp_f32 %0, %1" : "=v"(pv[r]) : "v"(sc[r]));
      // tree-sum of 16
      float s8[8], s4[4], s2[2];
#pragma unroll
      for (int g = 0; g < 8; g++) s8[g] = pv[2 * g] + pv[2 * g + 1];
#pragma unroll
      for (int g = 0; g < 4; g++) s4[g] = s8[2 * g] + s8[2 * g + 1];
      s2[0] = s4[0] + s4[1]; s2[1] = s4[2] + s4[3];
      Lp += s2[0] + s2[1];
      // pack to bf16 pairs: w0[g] -> t' = 8g+4h+{0,1}, w1[g] -> +{2,3}
      unsigned w0[4], w1[4];
#pragma unroll
      for (int g = 0; g < 4; g++) {
        asm("v_cvt_pk_bf16_f32 %0, %1, %2" : "=v"(w0[g]) : "v"(pv[4 * g]), "v"(pv[4 * g + 1]));
        asm("v_cvt_pk_bf16_f32 %0, %1, %2" : "=v"(w1[g]) : "v"(pv[4 * g + 2]), "v"(pv[4 * g + 3]));
      }
      // rebuild PV A-frags (k = t = 8h+j) via permlane32_swap (T12)
#pragma unroll
      for (int c = 0; c < 2; c++) {
        unsigned a0 = w0[2 * c], b0 = w0[2 * c + 1];
        unsigned a1 = w1[2 * c], b1 = w1[2 * c + 1];
        asm("v_permlane32_swap_b32 %0, %1" : "+v"(a0), "+v"(b0));
        asm("v_permlane32_swap_b32 %0, %1" : "+v"(a1), "+v"(b1));
        u32x4 up; up[0] = a0; up[1] = a1; up[2] = b0; up[3] = b1;
        bh8 pa = __builtin_bit_cast(bh8, up);
        __builtin_amdgcn_s_setprio(1);
#pragma unroll
        for (int ni = 0; ni < 2; ni++) {
          int d = ni * 32 + lq;
          int slot = (4 * tsb + 2 * c + h) ^ swz8(d);
          bh8 vf = *(const bh8*)(Vc + d * 128 + slot * 16);
          O[ni] = __builtin_amdgcn_mfma_f32_32x32x16_bf16(pa, vf, O[ni], 0, 0, 0);
        }
        __builtin_amdgcn_s_setprio(0);
      }
    }
  }

  // denominators: partner lane (q+32 half) holds the other 16 t' per subtile
  float Lt = Lp + __shfl_xor(Lp, 32);
  if (l < 32) Lbuf[w][l] = Lt;        // intra-wave LDS: program order suffices
  f32x4v Lq[4];
#pragma unroll
  for (int rq = 0; rq < 4; rq++) Lq[rq] = *(const f32x4v*)&Lbuf[w][4 * h + 8 * rq];
  float rl[16];
#pragma unroll
  for (int rq = 0; rq < 4; rq++)
#pragma unroll
    for (int j = 0; j < 4; j++) rl[4 * rq + j] = __builtin_amdgcn_rcpf(Lq[rq][j]);

  const int b = bh >> 4, hh = bh & 15;
#pragma unroll
  for (int ni = 0; ni < 2; ni++) {
    int d = ni * 32 + lq;
#pragma unroll
    for (int r = 0; r < 16; r++) {
      float vvv = O[ni][r] * rl[4 * (r >> 2) + (r & 3)];
      int qg = q0 + 4 * h + 8 * (r >> 2) + (r & 3);
      vals[((size_t)(b * S_ + qg)) * D_ + hh * HD_ + d] = f2bf(vvv);
    }
  }
}

// ---------- launch ----------
extern "C" void kernel_launch(void* const* d_in, const int* in_sizes, int n_in,
                              void* d_out, int out_size, void* d_ws, size_t ws_size,
                              hipStream_t stream) {
  const float* x     = (const float*)d_in[0];
  const float* qkv_w = (const float*)d_in[1];
  const float* qkv_b = (const float*)d_in[2];
  const float* out_w = (const float*)d_in[3];
  const float* out_b = (const float*)d_in[4];
  float* out = (float*)d_out;

  unsigned short* xb  = (unsigned short*)d_ws;                 // 8 MB  x bf16 [4096][1024]
  unsigned short* qwb = xb  + (size_t)4096 * 1024;             // 6 MB  qkv_w bf16
  unsigned short* owb = qwb + (size_t)3072 * 1024;             // 2 MB  out_w bf16
  unsigned short* Qb  = owb + (size_t)1024 * 1024;             // 8 MB  Q*C2 [32][2048][64]
  unsigned short* Kb  = Qb  + (size_t)32 * 2048 * 64;          // 8 MB  K [32][2048][64]
  unsigned short* Vb  = Kb  + (size_t)32 * 2048 * 64;          // 8 MB  V^T [32][64][2048]
  unsigned short* vb  = Vb  + (size_t)32 * 2048 * 64;          // 8 MB  vals bf16

  cvt_all<<<8192, 256, 0, stream>>>(x, qkv_w, out_w, xb, qwb, owb);
  gemm_bt<0><<<dim3(32, 24), 256, 0, stream>>>(xb, qwb, qkv_b, nullptr, Qb, Kb, Vb,
                                               4096, 3072, 1024);
  attn_fwd<<<512, 256, 0, stream>>>(Qb, Kb, Vb, vb);
  gemm_bt<1><<<dim3(32, 8), 256, 0, stream>>>(vb, owb, out_b, out, nullptr, nullptr, nullptr,
                                              4096, 1024, 1024);
}

// Round 6
// 120.512 us; speedup vs baseline: 1.3137x; 1.0222x over previous
//
#include <hip/hip_runtime.h>

// ---------- types ----------
using bh8    = __attribute__((ext_vector_type(8)))  short;          // 8 bf16 (4 VGPR)
using f32x4v = __attribute__((ext_vector_type(4)))  float;
using f32x16 = __attribute__((ext_vector_type(16))) float;
using u32x4  = __attribute__((ext_vector_type(4)))  unsigned int;
using us4    = __attribute__((ext_vector_type(4)))  unsigned short;

#define AS1 __attribute__((address_space(1)))
#define AS3 __attribute__((address_space(3)))

#define B_  2
#define S_  2048
#define D_  1024
#define H_  16
#define HD_ 64
#define C2A 0.0360673760222241f   // 0.2/sqrt(64) * log2(e), folded into Q

__device__ __forceinline__ unsigned short f2bf(float f) {
  unsigned u = __builtin_bit_cast(unsigned, f);
  return (unsigned short)((u + 0x7fffu + ((u >> 16) & 1u)) >> 16);   // RNE
}
__device__ __forceinline__ int swz8(int r) { return (r ^ (r >> 3)) & 7; }

// ---------- fused f32 -> bf16 convert (x, qkv_w, out_w in one launch) ----------
__global__ __launch_bounds__(256) void cvt_all(const float* __restrict__ x,
                                               const float* __restrict__ qw,
                                               const float* __restrict__ ow,
                                               unsigned short* __restrict__ xb,
                                               unsigned short* __restrict__ qwb,
                                               unsigned short* __restrict__ owb) {
  int i = blockIdx.x * 256 + threadIdx.x;     // vec4 index over 8M floats
  const float* src; unsigned short* dst; int off;
  if (i < 1048576)      { src = x;  dst = xb;  off = i; }
  else if (i < 1835008) { src = qw; dst = qwb; off = i - 1048576; }
  else                  { src = ow; dst = owb; off = i - 1835008; }
  f32x4v v = reinterpret_cast<const f32x4v*>(src)[off];
  us4 o;
  o[0] = f2bf(v[0]); o[1] = f2bf(v[1]); o[2] = f2bf(v[2]); o[3] = f2bf(v[3]);
  reinterpret_cast<us4*>(dst)[off] = o;
}

// ---------- GEMM: C[m,e] = sum_k A[m,k]*B[e,k] (+bias) ----------
// MODE 0: scatter bf16: Q (scaled by C2A) [bh][s][64], K [bh][s][64], V^T [bh][d][S]
// MODE 1: f32 out C[m*N+e] (+bias)
template <int MODE>
__global__ __launch_bounds__(256) void gemm_bt(const unsigned short* __restrict__ A,
                                               const unsigned short* __restrict__ Bw,
                                               const float* __restrict__ bias,
                                               float* __restrict__ Cf,
                                               unsigned short* __restrict__ Qo,
                                               unsigned short* __restrict__ Ko,
                                               unsigned short* __restrict__ Vo,
                                               int M, int N, int K) {
  __shared__ __align__(16) short As[128 * 64];
  __shared__ __align__(16) short Bs[128 * 64];
  const int tid = threadIdx.x;
  const int w = tid >> 6, l = tid & 63;
  const int lr = l & 15, lg = l >> 4;
  const int m0 = blockIdx.x * 128, n0 = blockIdx.y * 128;
  const int wm = (w >> 1) * 64, wn = (w & 1) * 64;

  f32x4v acc[4][4];
#pragma unroll
  for (int a = 0; a < 4; a++)
#pragma unroll
    for (int b = 0; b < 4; b++)
#pragma unroll
      for (int r = 0; r < 4; r++) acc[a][b][r] = 0.f;

#pragma unroll 1
  for (int k0 = 0; k0 < K; k0 += 64) {
    __syncthreads();
#pragma unroll
    for (int n = 0; n < 4; n++) {
      int idx = n * 256 + tid;
      int row = idx >> 3, p = idx & 7;
      int c = p ^ swz8(row);
      const unsigned short* srcA = A + (size_t)(m0 + row) * K + k0 + c * 8;
      const unsigned short* srcB = Bw + (size_t)(n0 + row) * K + k0 + c * 8;
      __builtin_amdgcn_global_load_lds((const AS1 void*)srcA,
          (AS3 void*)((char*)As + (n * 256 + w * 64) * 16), 16, 0, 0);
      __builtin_amdgcn_global_load_lds((const AS1 void*)srcB,
          (AS3 void*)((char*)Bs + (n * 256 + w * 64) * 16), 16, 0, 0);
    }
    __syncthreads();
#pragma unroll
    for (int kk = 0; kk < 2; kk++) {
      bh8 af[4], bf[4];
#pragma unroll
      for (int mi = 0; mi < 4; mi++) {
        int row = wm + mi * 16 + lr;
        int slot = (4 * kk + lg) ^ swz8(row);
        af[mi] = *(const bh8*)((const char*)As + row * 128 + slot * 16);
      }
#pragma unroll
      for (int ni = 0; ni < 4; ni++) {
        int row = wn + ni * 16 + lr;
        int slot = (4 * kk + lg) ^ swz8(row);
        bf[ni] = *(const bh8*)((const char*)Bs + row * 128 + slot * 16);
      }
#pragma unroll
      for (int mi = 0; mi < 4; mi++)
#pragma unroll
        for (int ni = 0; ni < 4; ni++)
          acc[mi][ni] = __builtin_amdgcn_mfma_f32_16x16x32_bf16(af[mi], bf[ni], acc[mi][ni], 0, 0, 0);
    }
  }

  // D layout (16x16): col=e=lane&15, row=m=(lane>>4)*4+r  [m89]
  if (MODE == 1) {
#pragma unroll
    for (int ni = 0; ni < 4; ni++) {
      int e = n0 + wn + ni * 16 + lr;
      float bv = bias[e];
#pragma unroll
      for (int mi = 0; mi < 4; mi++) {
        int mbase = m0 + wm + mi * 16 + lg * 4;
#pragma unroll
        for (int r = 0; r < 4; r++)
          Cf[(size_t)(mbase + r) * N + e] = acc[mi][ni][r] + bv;
      }
    }
  } else {
#pragma unroll
    for (int ni = 0; ni < 4; ni++) {
      int e = n0 + wn + ni * 16 + lr;
      int hh = e / 192;
      int rr = e - hh * 192;
      int tsel = rr >> 6, d = rr & 63;
      float bv = bias[e];
#pragma unroll
      for (int mi = 0; mi < 4; mi++) {
        int mbase = m0 + wm + mi * 16 + lg * 4;
#pragma unroll
        for (int r = 0; r < 4; r++) {
          int m = mbase + r;
          int b = m >> 11, s = m & 2047;
          float val = acc[mi][ni][r] + bv;
          size_t bh = (size_t)(b * H_ + hh);
          if (tsel == 0)      Qo[(bh * S_ + s) * HD_ + d] = f2bf(val * C2A);
          else if (tsel == 1) Ko[(bh * S_ + s) * HD_ + d] = f2bf(val);
          else                Vo[(bh * HD_ + d) * S_ + s] = f2bf(val);   // V^T
        }
      }
    }
  }
}

// ---------- fused attention ----------
// grid 512 (XCD-swizzled), 256 thr = 4 waves, wave owns 32 q-rows.
// swapped scores: S^T = mfma(K_frag, Q_frag); Q pre-scaled -> exp direct.
// K [t][d] and V^T [d][t] staged via global_load_lds, double-buffered.
// Softmax denominator computed on the MATRIX pipe: Ol = mfma(pa, ONES, Ol)
// gives Ol[r] = sum_t P[q_r, t] in the same r-layout as O — no tree-sum,
// no shfl, no LDS round trip.
__global__ __launch_bounds__(256) void attn_fwd(const unsigned short* __restrict__ Qt,
                                                const unsigned short* __restrict__ Kt,
                                                const unsigned short* __restrict__ VT,
                                                unsigned short* __restrict__ vals) {
  __shared__ __align__(16) short Ks[2 * 64 * 64];   // 16KB double-buffered
  __shared__ __align__(16) short Vs[2 * 64 * 64];   // 16KB
  const int tid = threadIdx.x, w = tid >> 6, l = tid & 63;
  const int lq = l & 31, h = l >> 5;
  // XCD swizzle: all 16 q-blocks of a (b,h) land on one XCD (same lin%8)
  const int lin = blockIdx.x;
  const int uu_ = lin >> 3;
  const int bh = (lin & 7) + 8 * (uu_ & 3);
  const int q0 = (uu_ >> 2) * 128 + w * 32;
  const unsigned short* Qp = Qt + (size_t)bh * (S_ * HD_);
  const unsigned short* Kp = Kt + (size_t)bh * (S_ * HD_);
  const unsigned short* Vp = VT + (size_t)bh * (HD_ * S_);

  bh8 qf[4];  // B-frags: col=q=lane&31, k=d=(lane>>5)*8+j
#pragma unroll
  for (int kf = 0; kf < 4; kf++)
    qf[kf] = *(const bh8*)(Qp + (size_t)(q0 + lq) * HD_ + kf * 16 + h * 8);

  // persistent zero C-operand (avoids 16 v_movs per sc init)
  f32x16 KZ;
#pragma unroll
  for (int r = 0; r < 16; r++) KZ[r] = 0.f;
  // bf16 1.0 x8 for the L-row MFMA
  bh8 ones;
#pragma unroll
  for (int j = 0; j < 8; j++) ones[j] = (short)0x3F80;

  f32x16 O[2], Ol;
  O[0] = KZ; O[1] = KZ; Ol = KZ;

  // per-thread staging addresses (fixed; advance by tile)
  const int row0 = tid >> 3,        c0 = (tid & 7) ^ swz8(row0);
  const int row1 = (256 + tid) >> 3, c1 = (tid & 7) ^ swz8(row1);
  const unsigned short* kp0 = Kp + row0 * HD_ + c0 * 8;
  const unsigned short* kp1 = Kp + row1 * HD_ + c1 * 8;
  const unsigned short* vp0 = Vp + (size_t)row0 * S_ + c0 * 8;
  const unsigned short* vp1 = Vp + (size_t)row1 * S_ + c1 * 8;
  char* dK = (char*)Ks + w * 64 * 16;
  char* dV = (char*)Vs + w * 64 * 16;

  auto stage = [&](int t, int buf) {
    __builtin_amdgcn_global_load_lds((const AS1 void*)(kp0 + (size_t)t * 4096),
                                     (AS3 void*)(dK + buf * 8192), 16, 0, 0);
    __builtin_amdgcn_global_load_lds((const AS1 void*)(kp1 + (size_t)t * 4096),
                                     (AS3 void*)(dK + buf * 8192 + 4096), 16, 0, 0);
    __builtin_amdgcn_global_load_lds((const AS1 void*)(vp0 + (size_t)t * 64),
                                     (AS3 void*)(dV + buf * 8192), 16, 0, 0);
    __builtin_amdgcn_global_load_lds((const AS1 void*)(vp1 + (size_t)t * 64),
                                     (AS3 void*)(dV + buf * 8192 + 4096), 16, 0, 0);
  };

  stage(0, 0);
#pragma unroll 1
  for (int i = 0; i < 32; i++) {
    const int cur = i & 1;
    asm volatile("s_waitcnt vmcnt(0)" ::: "memory");   // my tile-i staging done
    __builtin_amdgcn_s_barrier();                      // everyone staged; prev-buf readers done
    if (i < 31) stage(i + 1, cur ^ 1);                 // prefetch flies under compute
    const char* Kc = (const char*)Ks + cur * 8192;
    const char* Vc = (const char*)Vs + cur * 8192;
#pragma unroll
    for (int tsb = 0; tsb < 2; tsb++) {
      const int ts = tsb * 32;
      const int row = ts + lq;
      f32x16 sc;
      __builtin_amdgcn_s_setprio(1);
      {
        int slot = h ^ swz8(row);                      // kf = 0
        bh8 kfr = *(const bh8*)(Kc + row * 128 + slot * 16);
        sc = __builtin_amdgcn_mfma_f32_32x32x16_bf16(kfr, qf[0], KZ, 0, 0, 0);
      }
#pragma unroll
      for (int kf = 1; kf < 4; kf++) {
        int slot = (2 * kf + h) ^ swz8(row);
        bh8 kfr = *(const bh8*)(Kc + row * 128 + slot * 16);
        sc = __builtin_amdgcn_mfma_f32_32x32x16_bf16(kfr, qf[kf], sc, 0, 0, 0);
      }
      __builtin_amdgcn_s_setprio(0);
      // lane holds P[q=lq][t' = (r&3)+8*(r>>2)+4h]; exponent already scaled
      float pv[16];
#pragma unroll
      for (int r = 0; r < 16; r++)
        asm("v_exp_f32 %0, %1" : "=v"(pv[r]) : "v"(sc[r]));
      // pack to bf16 pairs: w0[g] -> t' = 8g+4h+{0,1}, w1[g] -> +{2,3}
      unsigned w0[4], w1[4];
#pragma unroll
      for (int g = 0; g < 4; g++) {
        asm("v_cvt_pk_bf16_f32 %0, %1, %2" : "=v"(w0[g]) : "v"(pv[4 * g]), "v"(pv[4 * g + 1]));
        asm("v_cvt_pk_bf16_f32 %0, %1, %2" : "=v"(w1[g]) : "v"(pv[4 * g + 2]), "v"(pv[4 * g + 3]));
      }
      // rebuild PV A-frags (k = t = 8h+j) via permlane32_swap (T12)
#pragma unroll
      for (int c = 0; c < 2; c++) {
        unsigned a0 = w0[2 * c], b0 = w0[2 * c + 1];
        unsigned a1 = w1[2 * c], b1 = w1[2 * c + 1];
        asm("v_permlane32_swap_b32 %0, %1" : "+v"(a0), "+v"(b0));
        asm("v_permlane32_swap_b32 %0, %1" : "+v"(a1), "+v"(b1));
        u32x4 up; up[0] = a0; up[1] = a1; up[2] = b0; up[3] = b1;
        bh8 pa = __builtin_bit_cast(bh8, up);
        __builtin_amdgcn_s_setprio(1);
#pragma unroll
        for (int ni = 0; ni < 2; ni++) {
          int d = ni * 32 + lq;
          int slot = (4 * tsb + 2 * c + h) ^ swz8(d);
          bh8 vf = *(const bh8*)(Vc + d * 128 + slot * 16);
          O[ni] = __builtin_amdgcn_mfma_f32_32x32x16_bf16(pa, vf, O[ni], 0, 0, 0);
        }
        Ol = __builtin_amdgcn_mfma_f32_32x32x16_bf16(pa, ones, Ol, 0, 0, 0);
        __builtin_amdgcn_s_setprio(0);
      }
    }
  }

  // denominators already in Ol[r] = L[q_r] (replicated across lanes)
  float rl[16];
#pragma unroll
  for (int r = 0; r < 16; r++) rl[r] = __builtin_amdgcn_rcpf(Ol[r]);

  const int b = bh >> 4, hh = bh & 15;
#pragma unroll
  for (int ni = 0; ni < 2; ni++) {
    int d = ni * 32 + lq;
#pragma unroll
    for (int r = 0; r < 16; r++) {
      float vvv = O[ni][r] * rl[r];
      int qg = q0 + 4 * h + 8 * (r >> 2) + (r & 3);
      vals[((size_t)(b * S_ + qg)) * D_ + hh * HD_ + d] = f2bf(vvv);
    }
  }
}

// ---------- launch ----------
extern "C" void kernel_launch(void* const* d_in, const int* in_sizes, int n_in,
                              void* d_out, int out_size, void* d_ws, size_t ws_size,
                              hipStream_t stream) {
  const float* x     = (const float*)d_in[0];
  const float* qkv_w = (const float*)d_in[1];
  const float* qkv_b = (const float*)d_in[2];
  const float* out_w = (const float*)d_in[3];
  const float* out_b = (const float*)d_in[4];
  float* out = (float*)d_out;

  unsigned short* xb  = (unsigned short*)d_ws;                 // 8 MB  x bf16 [4096][1024]
  unsigned short* qwb = xb  + (size_t)4096 * 1024;             // 6 MB  qkv_w bf16
  unsigned short* owb = qwb + (size_t)3072 * 1024;             // 2 MB  out_w bf16
  unsigned short* Qb  = owb + (size_t)1024 * 1024;             // 8 MB  Q*C2 [32][2048][64]
  unsigned short* Kb  = Qb  + (size_t)32 * 2048 * 64;          // 8 MB  K [32][2048][64]
  unsigned short* Vb  = Kb  + (size_t)32 * 2048 * 64;          // 8 MB  V^T [32][64][2048]
  unsigned short* vb  = Vb  + (size_t)32 * 2048 * 64;          // 8 MB  vals bf16

  cvt_all<<<8192, 256, 0, stream>>>(x, qkv_w, out_w, xb, qwb, owb);
  gemm_bt<0><<<dim3(32, 24), 256, 0, stream>>>(xb, qwb, qkv_b, nullptr, Qb, Kb, Vb,
                                               4096, 3072, 1024);
  attn_fwd<<<512, 256, 0, stream>>>(Qb, Kb, Vb, vb);
  gemm_bt<1><<<dim3(32, 8), 256, 0, stream>>>(vb, owb, out_b, out, nullptr, nullptr, nullptr,
                                              4096, 1024, 1024);
}

// Round 7
// 120.151 us; speedup vs baseline: 1.3176x; 1.0030x over previous
//
#include <hip/hip_runtime.h>

// ---------- types ----------
using bh8    = __attribute__((ext_vector_type(8)))  short;          // 8 bf16 (4 VGPR)
using f32x4v = __attribute__((ext_vector_type(4)))  float;
using f32x16 = __attribute__((ext_vector_type(16))) float;
using u32x4  = __attribute__((ext_vector_type(4)))  unsigned int;
using us4    = __attribute__((ext_vector_type(4)))  unsigned short;

#define AS1 __attribute__((address_space(1)))
#define AS3 __attribute__((address_space(3)))

#define B_  2
#define S_  2048
#define D_  1024
#define H_  16
#define HD_ 64
#define C2A 0.0360673760222241f   // 0.2/sqrt(64) * log2(e), folded into Q

__device__ __forceinline__ unsigned short f2bf(float f) {
  unsigned u = __builtin_bit_cast(unsigned, f);
  return (unsigned short)((u + 0x7fffu + ((u >> 16) & 1u)) >> 16);   // RNE
}
__device__ __forceinline__ int swz8(int r) { return (r ^ (r >> 3)) & 7; }

// ---------- fused f32 -> bf16 convert (x, qkv_w, out_w in one launch) ----------
__global__ __launch_bounds__(256) void cvt_all(const float* __restrict__ x,
                                               const float* __restrict__ qw,
                                               const float* __restrict__ ow,
                                               unsigned short* __restrict__ xb,
                                               unsigned short* __restrict__ qwb,
                                               unsigned short* __restrict__ owb) {
  int i = blockIdx.x * 256 + threadIdx.x;     // vec4 index over 8M floats
  const float* src; unsigned short* dst; int off;
  if (i < 1048576)      { src = x;  dst = xb;  off = i; }
  else if (i < 1835008) { src = qw; dst = qwb; off = i - 1048576; }
  else                  { src = ow; dst = owb; off = i - 1835008; }
  f32x4v v = reinterpret_cast<const f32x4v*>(src)[off];
  us4 o;
  o[0] = f2bf(v[0]); o[1] = f2bf(v[1]); o[2] = f2bf(v[2]); o[3] = f2bf(v[3]);
  reinterpret_cast<us4*>(dst)[off] = o;
}

// ---------- GEMM: C[m,e] = sum_k A[m,k]*B[e,k] (+bias) ----------
// MODE 0: scatter bf16: Q (scaled by C2A) [bh][s][64], K [bh][s][64], V^T [bh][d][S]
// MODE 1: f32 out C[m*N+e] (+bias)
template <int MODE>
__global__ __launch_bounds__(256) void gemm_bt(const unsigned short* __restrict__ A,
                                               const unsigned short* __restrict__ Bw,
                                               const float* __restrict__ bias,
                                               float* __restrict__ Cf,
                                               unsigned short* __restrict__ Qo,
                                               unsigned short* __restrict__ Ko,
                                               unsigned short* __restrict__ Vo,
                                               int M, int N, int K) {
  __shared__ __align__(16) short As[128 * 64];
  __shared__ __align__(16) short Bs[128 * 64];
  const int tid = threadIdx.x;
  const int w = tid >> 6, l = tid & 63;
  const int lr = l & 15, lg = l >> 4;
  const int m0 = blockIdx.x * 128, n0 = blockIdx.y * 128;
  const int wm = (w >> 1) * 64, wn = (w & 1) * 64;

  f32x4v acc[4][4];
#pragma unroll
  for (int a = 0; a < 4; a++)
#pragma unroll
    for (int b = 0; b < 4; b++)
#pragma unroll
      for (int r = 0; r < 4; r++) acc[a][b][r] = 0.f;

#pragma unroll 1
  for (int k0 = 0; k0 < K; k0 += 64) {
    __syncthreads();
#pragma unroll
    for (int n = 0; n < 4; n++) {
      int idx = n * 256 + tid;
      int row = idx >> 3, p = idx & 7;
      int c = p ^ swz8(row);
      const unsigned short* srcA = A + (size_t)(m0 + row) * K + k0 + c * 8;
      const unsigned short* srcB = Bw + (size_t)(n0 + row) * K + k0 + c * 8;
      __builtin_amdgcn_global_load_lds((const AS1 void*)srcA,
          (AS3 void*)((char*)As + (n * 256 + w * 64) * 16), 16, 0, 0);
      __builtin_amdgcn_global_load_lds((const AS1 void*)srcB,
          (AS3 void*)((char*)Bs + (n * 256 + w * 64) * 16), 16, 0, 0);
    }
    __syncthreads();
#pragma unroll
    for (int kk = 0; kk < 2; kk++) {
      bh8 af[4], bf[4];
#pragma unroll
      for (int mi = 0; mi < 4; mi++) {
        int row = wm + mi * 16 + lr;
        int slot = (4 * kk + lg) ^ swz8(row);
        af[mi] = *(const bh8*)((const char*)As + row * 128 + slot * 16);
      }
#pragma unroll
      for (int ni = 0; ni < 4; ni++) {
        int row = wn + ni * 16 + lr;
        int slot = (4 * kk + lg) ^ swz8(row);
        bf[ni] = *(const bh8*)((const char*)Bs + row * 128 + slot * 16);
      }
#pragma unroll
      for (int mi = 0; mi < 4; mi++)
#pragma unroll
        for (int ni = 0; ni < 4; ni++)
          acc[mi][ni] = __builtin_amdgcn_mfma_f32_16x16x32_bf16(af[mi], bf[ni], acc[mi][ni], 0, 0, 0);
    }
  }

  // D layout (16x16): col=e=lane&15, row=m=(lane>>4)*4+r  [m89]
  if (MODE == 1) {
#pragma unroll
    for (int ni = 0; ni < 4; ni++) {
      int e = n0 + wn + ni * 16 + lr;
      float bv = bias[e];
#pragma unroll
      for (int mi = 0; mi < 4; mi++) {
        int mbase = m0 + wm + mi * 16 + lg * 4;
#pragma unroll
        for (int r = 0; r < 4; r++)
          Cf[(size_t)(mbase + r) * N + e] = acc[mi][ni][r] + bv;
      }
    }
  } else {
#pragma unroll
    for (int ni = 0; ni < 4; ni++) {
      int e = n0 + wn + ni * 16 + lr;
      int hh = e / 192;
      int rr = e - hh * 192;
      int tsel = rr >> 6, d = rr & 63;
      float bv = bias[e];
#pragma unroll
      for (int mi = 0; mi < 4; mi++) {
        int mbase = m0 + wm + mi * 16 + lg * 4;
#pragma unroll
        for (int r = 0; r < 4; r++) {
          int m = mbase + r;
          int b = m >> 11, s = m & 2047;
          float val = acc[mi][ni][r] + bv;
          size_t bh = (size_t)(b * H_ + hh);
          if (tsel == 0)      Qo[(bh * S_ + s) * HD_ + d] = f2bf(val * C2A);
          else if (tsel == 1) Ko[(bh * S_ + s) * HD_ + d] = f2bf(val);
          else                Vo[(bh * HD_ + d) * S_ + s] = f2bf(val);   // V^T
        }
      }
    }
  }
}

// ---------- fused attention ----------
// grid 512 (XCD-swizzled), 256 thr = 4 waves, wave owns 32 q-rows.
// swapped scores: S^T = mfma(K_frag, Q_frag); Q pre-scaled -> exp direct.
// K [t][d] and V^T [d][t] staged via global_load_lds, double-buffered.
// Denominator on matrix pipe: Ol = mfma(pa, ONES, Ol).
// DUAL-CHAIN inner loop: both 32-t sub-tiles as straight-line independent
// chains (QK0,QK1,exp0,pack0,exp1,pack1,PV0,PV1) so the scheduler overlaps
// VALU/trans of one chain with MFMA of the other. Same ops, same accumulation
// order as R6 — bit-identical result.
__global__ __launch_bounds__(256) void attn_fwd(const unsigned short* __restrict__ Qt,
                                                const unsigned short* __restrict__ Kt,
                                                const unsigned short* __restrict__ VT,
                                                unsigned short* __restrict__ vals) {
  __shared__ __align__(16) short Ks[2 * 64 * 64];   // 16KB double-buffered
  __shared__ __align__(16) short Vs[2 * 64 * 64];   // 16KB
  const int tid = threadIdx.x, w = tid >> 6, l = tid & 63;
  const int lq = l & 31, h = l >> 5;
  // XCD swizzle: all 16 q-blocks of a (b,h) land on one XCD (same lin%8)
  const int lin = blockIdx.x;
  const int uu_ = lin >> 3;
  const int bh = (lin & 7) + 8 * (uu_ & 3);
  const int q0 = (uu_ >> 2) * 128 + w * 32;
  const unsigned short* Qp = Qt + (size_t)bh * (S_ * HD_);
  const unsigned short* Kp = Kt + (size_t)bh * (S_ * HD_);
  const unsigned short* Vp = VT + (size_t)bh * (HD_ * S_);

  bh8 qf[4];  // B-frags: col=q=lane&31, k=d=(lane>>5)*8+j
#pragma unroll
  for (int kf = 0; kf < 4; kf++)
    qf[kf] = *(const bh8*)(Qp + (size_t)(q0 + lq) * HD_ + kf * 16 + h * 8);

  // persistent zero C-operand
  f32x16 KZ;
#pragma unroll
  for (int r = 0; r < 16; r++) KZ[r] = 0.f;
  bh8 ones;
#pragma unroll
  for (int j = 0; j < 8; j++) ones[j] = (short)0x3F80;

  f32x16 O[2], Ol;
  O[0] = KZ; O[1] = KZ; Ol = KZ;

  // per-thread staging addresses (fixed; advance by tile)
  const int row0 = tid >> 3,        c0 = (tid & 7) ^ swz8(row0);
  const int row1 = (256 + tid) >> 3, c1 = (tid & 7) ^ swz8(row1);
  const unsigned short* kp0 = Kp + row0 * HD_ + c0 * 8;
  const unsigned short* kp1 = Kp + row1 * HD_ + c1 * 8;
  const unsigned short* vp0 = Vp + (size_t)row0 * S_ + c0 * 8;
  const unsigned short* vp1 = Vp + (size_t)row1 * S_ + c1 * 8;
  char* dK = (char*)Ks + w * 64 * 16;
  char* dV = (char*)Vs + w * 64 * 16;

  auto stage = [&](int t, int buf) {
    __builtin_amdgcn_global_load_lds((const AS1 void*)(kp0 + (size_t)t * 4096),
                                     (AS3 void*)(dK + buf * 8192), 16, 0, 0);
    __builtin_amdgcn_global_load_lds((const AS1 void*)(kp1 + (size_t)t * 4096),
                                     (AS3 void*)(dK + buf * 8192 + 4096), 16, 0, 0);
    __builtin_amdgcn_global_load_lds((const AS1 void*)(vp0 + (size_t)t * 64),
                                     (AS3 void*)(dV + buf * 8192), 16, 0, 0);
    __builtin_amdgcn_global_load_lds((const AS1 void*)(vp1 + (size_t)t * 64),
                                     (AS3 void*)(dV + buf * 8192 + 4096), 16, 0, 0);
  };

  // LDS read byte-offsets (loop-invariant)
  int ko0[4], ko1[4], vo0[4], vo1[4];
#pragma unroll
  for (int kf = 0; kf < 4; kf++) {
    int r0 = lq, r1 = 32 + lq;
    ko0[kf] = r0 * 128 + (((2 * kf + h) ^ swz8(r0)) << 4);
    ko1[kf] = r1 * 128 + (((2 * kf + h) ^ swz8(r1)) << 4);
  }
#pragma unroll
  for (int c = 0; c < 2; c++)
#pragma unroll
    for (int ni = 0; ni < 2; ni++) {
      int d = ni * 32 + lq;
      vo0[c * 2 + ni] = d * 128 + (((2 * c + h) ^ swz8(d)) << 4);
      vo1[c * 2 + ni] = d * 128 + (((4 + 2 * c + h) ^ swz8(d)) << 4);
    }

  stage(0, 0);
#pragma unroll 1
  for (int i = 0; i < 32; i++) {
    const int cur = i & 1;
    asm volatile("s_waitcnt vmcnt(0)" ::: "memory");   // my tile-i staging done
    __builtin_amdgcn_s_barrier();                      // everyone staged; prev-buf readers done
    if (i < 31) stage(i + 1, cur ^ 1);                 // prefetch flies under compute
    const char* Kc = (const char*)Ks + cur * 8192;
    const char* Vc = (const char*)Vs + cur * 8192;

    // ---- QK^T, both sub-tiles ----
    f32x16 sa, sb;
    __builtin_amdgcn_s_setprio(1);
    {
      bh8 k0 = *(const bh8*)(Kc + ko0[0]);
      bh8 k1 = *(const bh8*)(Kc + ko1[0]);
      sa = __builtin_amdgcn_mfma_f32_32x32x16_bf16(k0, qf[0], KZ, 0, 0, 0);
      sb = __builtin_amdgcn_mfma_f32_32x32x16_bf16(k1, qf[0], KZ, 0, 0, 0);
    }
#pragma unroll
    for (int kf = 1; kf < 4; kf++) {
      bh8 k0 = *(const bh8*)(Kc + ko0[kf]);
      bh8 k1 = *(const bh8*)(Kc + ko1[kf]);
      sa = __builtin_amdgcn_mfma_f32_32x32x16_bf16(k0, qf[kf], sa, 0, 0, 0);
      sb = __builtin_amdgcn_mfma_f32_32x32x16_bf16(k1, qf[kf], sb, 0, 0, 0);
    }
    __builtin_amdgcn_s_setprio(0);

    // ---- softmax numerators, chain 0 then chain 1 (independent) ----
    float pa_[16], pb_[16];
#pragma unroll
    for (int r = 0; r < 16; r++)
      asm("v_exp_f32 %0, %1" : "=v"(pa_[r]) : "v"(sa[r]));
    unsigned wa0[4], wa1[4];
#pragma unroll
    for (int g = 0; g < 4; g++) {
      asm("v_cvt_pk_bf16_f32 %0, %1, %2" : "=v"(wa0[g]) : "v"(pa_[4 * g]), "v"(pa_[4 * g + 1]));
      asm("v_cvt_pk_bf16_f32 %0, %1, %2" : "=v"(wa1[g]) : "v"(pa_[4 * g + 2]), "v"(pa_[4 * g + 3]));
    }
#pragma unroll
    for (int r = 0; r < 16; r++)
      asm("v_exp_f32 %0, %1" : "=v"(pb_[r]) : "v"(sb[r]));
    unsigned wb0[4], wb1[4];
#pragma unroll
    for (int g = 0; g < 4; g++) {
      asm("v_cvt_pk_bf16_f32 %0, %1, %2" : "=v"(wb0[g]) : "v"(pb_[4 * g]), "v"(pb_[4 * g + 1]));
      asm("v_cvt_pk_bf16_f32 %0, %1, %2" : "=v"(wb1[g]) : "v"(pb_[4 * g + 2]), "v"(pb_[4 * g + 3]));
    }

    // ---- rebuild PV A-frags via permlane32_swap (T12), both chains ----
    bh8 paf[2], pbf[2];
#pragma unroll
    for (int c = 0; c < 2; c++) {
      unsigned x0 = wa0[2 * c], y0 = wa0[2 * c + 1];
      unsigned x1 = wa1[2 * c], y1 = wa1[2 * c + 1];
      asm("v_permlane32_swap_b32 %0, %1" : "+v"(x0), "+v"(y0));
      asm("v_permlane32_swap_b32 %0, %1" : "+v"(x1), "+v"(y1));
      u32x4 up; up[0] = x0; up[1] = x1; up[2] = y0; up[3] = y1;
      paf[c] = __builtin_bit_cast(bh8, up);
    }
#pragma unroll
    for (int c = 0; c < 2; c++) {
      unsigned x0 = wb0[2 * c], y0 = wb0[2 * c + 1];
      unsigned x1 = wb1[2 * c], y1 = wb1[2 * c + 1];
      asm("v_permlane32_swap_b32 %0, %1" : "+v"(x0), "+v"(y0));
      asm("v_permlane32_swap_b32 %0, %1" : "+v"(x1), "+v"(y1));
      u32x4 up; up[0] = x0; up[1] = x1; up[2] = y0; up[3] = y1;
      pbf[c] = __builtin_bit_cast(bh8, up);
    }

    // ---- PV + L, both chains ----
    __builtin_amdgcn_s_setprio(1);
#pragma unroll
    for (int c = 0; c < 2; c++) {
      bh8 vf0 = *(const bh8*)(Vc + vo0[c * 2 + 0]);
      bh8 vf1 = *(const bh8*)(Vc + vo0[c * 2 + 1]);
      O[0] = __builtin_amdgcn_mfma_f32_32x32x16_bf16(paf[c], vf0, O[0], 0, 0, 0);
      O[1] = __builtin_amdgcn_mfma_f32_32x32x16_bf16(paf[c], vf1, O[1], 0, 0, 0);
      Ol   = __builtin_amdgcn_mfma_f32_32x32x16_bf16(paf[c], ones, Ol, 0, 0, 0);
    }
#pragma unroll
    for (int c = 0; c < 2; c++) {
      bh8 vf0 = *(const bh8*)(Vc + vo1[c * 2 + 0]);
      bh8 vf1 = *(const bh8*)(Vc + vo1[c * 2 + 1]);
      O[0] = __builtin_amdgcn_mfma_f32_32x32x16_bf16(pbf[c], vf0, O[0], 0, 0, 0);
      O[1] = __builtin_amdgcn_mfma_f32_32x32x16_bf16(pbf[c], vf1, O[1], 0, 0, 0);
      Ol   = __builtin_amdgcn_mfma_f32_32x32x16_bf16(pbf[c], ones, Ol, 0, 0, 0);
    }
    __builtin_amdgcn_s_setprio(0);
  }

  // denominators already in Ol[r] = L[q_r] (replicated across lanes)
  float rl[16];
#pragma unroll
  for (int r = 0; r < 16; r++) rl[r] = __builtin_amdgcn_rcpf(Ol[r]);

  const int b = bh >> 4, hh = bh & 15;
#pragma unroll
  for (int ni = 0; ni < 2; ni++) {
    int d = ni * 32 + lq;
#pragma unroll
    for (int r = 0; r < 16; r++) {
      float vvv = O[ni][r] * rl[r];
      int qg = q0 + 4 * h + 8 * (r >> 2) + (r & 3);
      vals[((size_t)(b * S_ + qg)) * D_ + hh * HD_ + d] = f2bf(vvv);
    }
  }
}

// ---------- launch ----------
extern "C" void kernel_launch(void* const* d_in, const int* in_sizes, int n_in,
                              void* d_out, int out_size, void* d_ws, size_t ws_size,
                              hipStream_t stream) {
  const float* x     = (const float*)d_in[0];
  const float* qkv_w = (const float*)d_in[1];
  const float* qkv_b = (const float*)d_in[2];
  const float* out_w = (const float*)d_in[3];
  const float* out_b = (const float*)d_in[4];
  float* out = (float*)d_out;

  unsigned short* xb  = (unsigned short*)d_ws;                 // 8 MB  x bf16 [4096][1024]
  unsigned short* qwb = xb  + (size_t)4096 * 1024;             // 6 MB  qkv_w bf16
  unsigned short* owb = qwb + (size_t)3072 * 1024;             // 2 MB  out_w bf16
  unsigned short* Qb  = owb + (size_t)1024 * 1024;             // 8 MB  Q*C2 [32][2048][64]
  unsigned short* Kb  = Qb  + (size_t)32 * 2048 * 64;          // 8 MB  K [32][2048][64]
  unsigned short* Vb  = Kb  + (size_t)32 * 2048 * 64;          // 8 MB  V^T [32][64][2048]
  unsigned short* vb  = Vb  + (size_t)32 * 2048 * 64;          // 8 MB  vals bf16

  cvt_all<<<8192, 256, 0, stream>>>(x, qkv_w, out_w, xb, qwb, owb);
  gemm_bt<0><<<dim3(32, 24), 256, 0, stream>>>(xb, qwb, qkv_b, nullptr, Qb, Kb, Vb,
                                               4096, 3072, 1024);
  attn_fwd<<<512, 256, 0, stream>>>(Qb, Kb, Vb, vb);
  gemm_bt<1><<<dim3(32, 8), 256, 0, stream>>>(vb, owb, out_b, out, nullptr, nullptr, nullptr,
                                              4096, 1024, 1024);
}

// Round 9
// 116.925 us; speedup vs baseline: 1.3539x; 1.0276x over previous
//
#include <hip/hip_runtime.h>

// ---------- types ----------
using bh8    = __attribute__((ext_vector_type(8)))  short;          // 8 bf16 (4 VGPR)
using f32x4v = __attribute__((ext_vector_type(4)))  float;
using f32x16 = __attribute__((ext_vector_type(16))) float;
using u32x4  = __attribute__((ext_vector_type(4)))  unsigned int;
using us4    = __attribute__((ext_vector_type(4)))  unsigned short;

#define AS1 __attribute__((address_space(1)))
#define AS3 __attribute__((address_space(3)))

#define B_  2
#define S_  2048
#define D_  1024
#define H_  16
#define HD_ 64
#define C2A 0.0360673760222241f   // 0.2/sqrt(64) * log2(e), folded into Q

__device__ __forceinline__ unsigned short f2bf(float f) {
  unsigned u = __builtin_bit_cast(unsigned, f);
  return (unsigned short)((u + 0x7fffu + ((u >> 16) & 1u)) >> 16);   // RNE
}
__device__ __forceinline__ int swz8(int r) { return (r ^ (r >> 3)) & 7; }

// ---------- fused f32 -> bf16 convert (x, qkv_w, out_w in one launch) ----------
__global__ __launch_bounds__(256) void cvt_all(const float* __restrict__ x,
                                               const float* __restrict__ qw,
                                               const float* __restrict__ ow,
                                               unsigned short* __restrict__ xb,
                                               unsigned short* __restrict__ qwb,
                                               unsigned short* __restrict__ owb) {
  int i = blockIdx.x * 256 + threadIdx.x;     // vec4 index over 8M floats
  const float* src; unsigned short* dst; int off;
  if (i < 1048576)      { src = x;  dst = xb;  off = i; }
  else if (i < 1835008) { src = qw; dst = qwb; off = i - 1048576; }
  else                  { src = ow; dst = owb; off = i - 1835008; }
  f32x4v v = reinterpret_cast<const f32x4v*>(src)[off];
  us4 o;
  o[0] = f2bf(v[0]); o[1] = f2bf(v[1]); o[2] = f2bf(v[2]); o[3] = f2bf(v[3]);
  reinterpret_cast<us4*>(dst)[off] = o;
}

// ---------- GEMM: C[m,e] = sum_k A[m,k]*B[e,k] (+bias) ----------
// MODE 0: scatter bf16: Q (scaled by C2A) [bh][s][64], K [bh][s][64], V^T [bh][d][S]
// MODE 1: f32 out C[m*N+e] (+bias)
// BM: 128 (waves 2x2, acc[4][4]) or 64 (waves 1x4, acc[4][2])
template <int MODE, int BM>
__global__ __launch_bounds__(256) void gemm_bt(const unsigned short* __restrict__ A,
                                               const unsigned short* __restrict__ Bw,
                                               const float* __restrict__ bias,
                                               float* __restrict__ Cf,
                                               unsigned short* __restrict__ Qo,
                                               unsigned short* __restrict__ Ko,
                                               unsigned short* __restrict__ Vo,
                                               int M, int N, int K) {
  constexpr int NIW = (BM == 128) ? 4 : 2;     // n-frags per wave
  constexpr int NA  = BM / 32;                 // A-staging issues: 256thr*16B = 4KB = 32 rows
  __shared__ __align__(16) short As[BM * 64];
  __shared__ __align__(16) short Bs[128 * 64];
  const int tid = threadIdx.x;
  const int w = tid >> 6, l = tid & 63;
  const int lr = l & 15, lg = l >> 4;
  const int m0 = blockIdx.x * BM, n0 = blockIdx.y * 128;
  const int wm = (BM == 128) ? (w >> 1) * 64 : 0;
  const int wn = (BM == 128) ? (w & 1) * 64 : w * 32;

  f32x4v acc[4][NIW];
#pragma unroll
  for (int a = 0; a < 4; a++)
#pragma unroll
    for (int b = 0; b < NIW; b++)
#pragma unroll
      for (int r = 0; r < 4; r++) acc[a][b][r] = 0.f;

#pragma unroll 1
  for (int k0 = 0; k0 < K; k0 += 64) {
    __syncthreads();
#pragma unroll
    for (int n = 0; n < NA; n++) {
      int idx = n * 256 + tid;
      int row = idx >> 3, p = idx & 7;
      int c = p ^ swz8(row);
      const unsigned short* srcA = A + (size_t)(m0 + row) * K + k0 + c * 8;
      __builtin_amdgcn_global_load_lds((const AS1 void*)srcA,
          (AS3 void*)((char*)As + (n * 256 + w * 64) * 16), 16, 0, 0);
    }
#pragma unroll
    for (int n = 0; n < 4; n++) {
      int idx = n * 256 + tid;
      int row = idx >> 3, p = idx & 7;
      int c = p ^ swz8(row);
      const unsigned short* srcB = Bw + (size_t)(n0 + row) * K + k0 + c * 8;
      __builtin_amdgcn_global_load_lds((const AS1 void*)srcB,
          (AS3 void*)((char*)Bs + (n * 256 + w * 64) * 16), 16, 0, 0);
    }
    __syncthreads();
#pragma unroll
    for (int kk = 0; kk < 2; kk++) {
      bh8 af[4], bf[NIW];
#pragma unroll
      for (int mi = 0; mi < 4; mi++) {
        int row = wm + mi * 16 + lr;
        int slot = (4 * kk + lg) ^ swz8(row);
        af[mi] = *(const bh8*)((const char*)As + row * 128 + slot * 16);
      }
#pragma unroll
      for (int ni = 0; ni < NIW; ni++) {
        int row = wn + ni * 16 + lr;
        int slot = (4 * kk + lg) ^ swz8(row);
        bf[ni] = *(const bh8*)((const char*)Bs + row * 128 + slot * 16);
      }
#pragma unroll
      for (int mi = 0; mi < 4; mi++)
#pragma unroll
        for (int ni = 0; ni < NIW; ni++)
          acc[mi][ni] = __builtin_amdgcn_mfma_f32_16x16x32_bf16(af[mi], bf[ni], acc[mi][ni], 0, 0, 0);
    }
  }

  // D layout (16x16): col=e=lane&15, row=m=(lane>>4)*4+r  [m89]
  if (MODE == 1) {
#pragma unroll
    for (int ni = 0; ni < NIW; ni++) {
      int e = n0 + wn + ni * 16 + lr;
      float bv = bias[e];
#pragma unroll
      for (int mi = 0; mi < 4; mi++) {
        int mbase = m0 + wm + mi * 16 + lg * 4;
#pragma unroll
        for (int r = 0; r < 4; r++)
          Cf[(size_t)(mbase + r) * N + e] = acc[mi][ni][r] + bv;
      }
    }
  } else {
#pragma unroll
    for (int ni = 0; ni < NIW; ni++) {
      int e = n0 + wn + ni * 16 + lr;
      int hh = e / 192;
      int rr = e - hh * 192;
      int tsel = rr >> 6, d = rr & 63;
      float bv = bias[e];
#pragma unroll
      for (int mi = 0; mi < 4; mi++) {
        int mbase = m0 + wm + mi * 16 + lg * 4;
#pragma unroll
        for (int r = 0; r < 4; r++) {
          int m = mbase + r;
          int b = m >> 11, s = m & 2047;
          float val = acc[mi][ni][r] + bv;
          size_t bh = (size_t)(b * H_ + hh);
          if (tsel == 0)      Qo[(bh * S_ + s) * HD_ + d] = f2bf(val * C2A);
          else if (tsel == 1) Ko[(bh * S_ + s) * HD_ + d] = f2bf(val);
          else                Vo[(bh * HD_ + d) * S_ + s] = f2bf(val);   // V^T
        }
      }
    }
  }
}

// ---------- fused attention ----------
// grid 256 (XCD-swizzled), 512 thr = 8 waves, each wave owns 32 q-rows and
// iterates ALL t (no t-split, no combine). Per-wave math identical to R7.
// K [t][d] and V^T [d][t] staged via global_load_lds (2 issues/thread),
// double-buffered; vmcnt(0)+barrier schedule unchanged.
__global__ __launch_bounds__(512) void attn_fwd(const unsigned short* __restrict__ Qt,
                                                const unsigned short* __restrict__ Kt,
                                                const unsigned short* __restrict__ VT,
                                                unsigned short* __restrict__ vals) {
  __shared__ __align__(16) short Ks[2 * 64 * 64];   // 16KB double-buffered
  __shared__ __align__(16) short Vs[2 * 64 * 64];   // 16KB
  const int tid = threadIdx.x, w = tid >> 6, l = tid & 63;
  const int lq = l & 31, h = l >> 5;
  // XCD swizzle: all 8 q-blocks of a (b,h) land on one XCD (same lin%8)
  const int lin = blockIdx.x;
  const int uu_ = lin >> 3;
  const int bh = (lin & 7) + 8 * (uu_ & 3);
  const int q0 = (uu_ >> 2) * 256 + w * 32;
  const unsigned short* Qp = Qt + (size_t)bh * (S_ * HD_);
  const unsigned short* Kp = Kt + (size_t)bh * (S_ * HD_);
  const unsigned short* Vp = VT + (size_t)bh * (HD_ * S_);

  bh8 qf[4];  // B-frags: col=q=lane&31, k=d=(lane>>5)*8+j
#pragma unroll
  for (int kf = 0; kf < 4; kf++)
    qf[kf] = *(const bh8*)(Qp + (size_t)(q0 + lq) * HD_ + kf * 16 + h * 8);

  // persistent zero C-operand
  f32x16 KZ;
#pragma unroll
  for (int r = 0; r < 16; r++) KZ[r] = 0.f;
  bh8 ones;
#pragma unroll
  for (int j = 0; j < 8; j++) ones[j] = (short)0x3F80;

  f32x16 O[2], Ol;
  O[0] = KZ; O[1] = KZ; Ol = KZ;

  // per-thread staging addresses (512 threads cover one 64x64 tile per region)
  const int row0 = tid >> 3, cc = (tid & 7) ^ swz8(row0);
  const unsigned short* kp0 = Kp + row0 * HD_ + cc * 8;
  const unsigned short* vp0 = Vp + (size_t)row0 * S_ + cc * 8;
  char* dK = (char*)Ks + w * 1024;
  char* dV = (char*)Vs + w * 1024;

  auto stage = [&](int t, int buf) {
    __builtin_amdgcn_global_load_lds((const AS1 void*)(kp0 + (size_t)t * 4096),
                                     (AS3 void*)(dK + buf * 8192), 16, 0, 0);
    __builtin_amdgcn_global_load_lds((const AS1 void*)(vp0 + (size_t)t * 64),
                                     (AS3 void*)(dV + buf * 8192), 16, 0, 0);
  };

  // LDS read byte-offsets (loop-invariant)
  int ko0[4], ko1[4], vo0[4], vo1[4];
#pragma unroll
  for (int kf = 0; kf < 4; kf++) {
    int r0 = lq, r1 = 32 + lq;
    ko0[kf] = r0 * 128 + (((2 * kf + h) ^ swz8(r0)) << 4);
    ko1[kf] = r1 * 128 + (((2 * kf + h) ^ swz8(r1)) << 4);
  }
#pragma unroll
  for (int c = 0; c < 2; c++)
#pragma unroll
    for (int ni = 0; ni < 2; ni++) {
      int d = ni * 32 + lq;
      vo0[c * 2 + ni] = d * 128 + (((2 * c + h) ^ swz8(d)) << 4);
      vo1[c * 2 + ni] = d * 128 + (((4 + 2 * c + h) ^ swz8(d)) << 4);
    }

  stage(0, 0);
#pragma unroll 1
  for (int i = 0; i < 32; i++) {
    const int cur = i & 1;
    asm volatile("s_waitcnt vmcnt(0)" ::: "memory");   // my tile-i staging done
    __builtin_amdgcn_s_barrier();                      // everyone staged; prev-buf readers done
    if (i < 31) stage(i + 1, cur ^ 1);                 // prefetch flies under compute
    const char* Kc = (const char*)Ks + cur * 8192;
    const char* Vc = (const char*)Vs + cur * 8192;

    // ---- QK^T, both sub-tiles ----
    f32x16 sa, sb;
    __builtin_amdgcn_s_setprio(1);
    {
      bh8 k0 = *(const bh8*)(Kc + ko0[0]);
      bh8 k1 = *(const bh8*)(Kc + ko1[0]);
      sa = __builtin_amdgcn_mfma_f32_32x32x16_bf16(k0, qf[0], KZ, 0, 0, 0);
      sb = __builtin_amdgcn_mfma_f32_32x32x16_bf16(k1, qf[0], KZ, 0, 0, 0);
    }
#pragma unroll
    for (int kf = 1; kf < 4; kf++) {
      bh8 k0 = *(const bh8*)(Kc + ko0[kf]);
      bh8 k1 = *(const bh8*)(Kc + ko1[kf]);
      sa = __builtin_amdgcn_mfma_f32_32x32x16_bf16(k0, qf[kf], sa, 0, 0, 0);
      sb = __builtin_amdgcn_mfma_f32_32x32x16_bf16(k1, qf[kf], sb, 0, 0, 0);
    }
    __builtin_amdgcn_s_setprio(0);

    // ---- softmax numerators, chain 0 then chain 1 (independent) ----
    float pa_[16], pb_[16];
#pragma unroll
    for (int r = 0; r < 16; r++)
      asm("v_exp_f32 %0, %1" : "=v"(pa_[r]) : "v"(sa[r]));
    unsigned wa0[4], wa1[4];
#pragma unroll
    for (int g = 0; g < 4; g++) {
      asm("v_cvt_pk_bf16_f32 %0, %1, %2" : "=v"(wa0[g]) : "v"(pa_[4 * g]), "v"(pa_[4 * g + 1]));
      asm("v_cvt_pk_bf16_f32 %0, %1, %2" : "=v"(wa1[g]) : "v"(pa_[4 * g + 2]), "v"(pa_[4 * g + 3]));
    }
#pragma unroll
    for (int r = 0; r < 16; r++)
      asm("v_exp_f32 %0, %1" : "=v"(pb_[r]) : "v"(sb[r]));
    unsigned wb0[4], wb1[4];
#pragma unroll
    for (int g = 0; g < 4; g++) {
      asm("v_cvt_pk_bf16_f32 %0, %1, %2" : "=v"(wb0[g]) : "v"(pb_[4 * g]), "v"(pb_[4 * g + 1]));
      asm("v_cvt_pk_bf16_f32 %0, %1, %2" : "=v"(wb1[g]) : "v"(pb_[4 * g + 2]), "v"(pb_[4 * g + 3]));
    }

    // ---- rebuild PV A-frags via permlane32_swap (T12), both chains ----
    bh8 paf[2], pbf[2];
#pragma unroll
    for (int c = 0; c < 2; c++) {
      unsigned x0 = wa0[2 * c], y0 = wa0[2 * c + 1];
      unsigned x1 = wa1[2 * c], y1 = wa1[2 * c + 1];
      asm("v_permlane32_swap_b32 %0, %1" : "+v"(x0), "+v"(y0));
      asm("v_permlane32_swap_b32 %0, %1" : "+v"(x1), "+v"(y1));
      u32x4 up; up[0] = x0; up[1] = x1; up[2] = y0; up[3] = y1;
      paf[c] = __builtin_bit_cast(bh8, up);
    }
#pragma unroll
    for (int c = 0; c < 2; c++) {
      unsigned x0 = wb0[2 * c], y0 = wb0[2 * c + 1];
      unsigned x1 = wb1[2 * c], y1 = wb1[2 * c + 1];
      asm("v_permlane32_swap_b32 %0, %1" : "+v"(x0), "+v"(y0));
      asm("v_permlane32_swap_b32 %0, %1" : "+v"(x1), "+v"(y1));
      u32x4 up; up[0] = x0; up[1] = x1; up[2] = y0; up[3] = y1;
      pbf[c] = __builtin_bit_cast(bh8, up);
    }

    // ---- PV + L, both chains ----
    __builtin_amdgcn_s_setprio(1);
#pragma unroll
    for (int c = 0; c < 2; c++) {
      bh8 vf0 = *(const bh8*)(Vc + vo0[c * 2 + 0]);
      bh8 vf1 = *(const bh8*)(Vc + vo0[c * 2 + 1]);
      O[0] = __builtin_amdgcn_mfma_f32_32x32x16_bf16(paf[c], vf0, O[0], 0, 0, 0);
      O[1] = __builtin_amdgcn_mfma_f32_32x32x16_bf16(paf[c], vf1, O[1], 0, 0, 0);
      Ol   = __builtin_amdgcn_mfma_f32_32x32x16_bf16(paf[c], ones, Ol, 0, 0, 0);
    }
#pragma unroll
    for (int c = 0; c < 2; c++) {
      bh8 vf0 = *(const bh8*)(Vc + vo1[c * 2 + 0]);
      bh8 vf1 = *(const bh8*)(Vc + vo1[c * 2 + 1]);
      O[0] = __builtin_amdgcn_mfma_f32_32x32x16_bf16(pbf[c], vf0, O[0], 0, 0, 0);
      O[1] = __builtin_amdgcn_mfma_f32_32x32x16_bf16(pbf[c], vf1, O[1], 0, 0, 0);
      Ol   = __builtin_amdgcn_mfma_f32_32x32x16_bf16(pbf[c], ones, Ol, 0, 0, 0);
    }
    __builtin_amdgcn_s_setprio(0);
  }

  // denominators already in Ol[r] = L[q_r] (replicated across lanes)
  float rl[16];
#pragma unroll
  for (int r = 0; r < 16; r++) rl[r] = __builtin_amdgcn_rcpf(Ol[r]);

  const int b = bh >> 4, hh = bh & 15;
#pragma unroll
  for (int ni = 0; ni < 2; ni++) {
    int d = ni * 32 + lq;
#pragma unroll
    for (int r = 0; r < 16; r++) {
      float vvv = O[ni][r] * rl[r];
      int qg = q0 + 4 * h + 8 * (r >> 2) + (r & 3);
      vals[((size_t)(b * S_ + qg)) * D_ + hh * HD_ + d] = f2bf(vvv);
    }
  }
}

// ---------- launch ----------
extern "C" void kernel_launch(void* const* d_in, const int* in_sizes, int n_in,
                              void* d_out, int out_size, void* d_ws, size_t ws_size,
                              hipStream_t stream) {
  const float* x     = (const float*)d_in[0];
  const float* qkv_w = (const float*)d_in[1];
  const float* qkv_b = (const float*)d_in[2];
  const float* out_w = (const float*)d_in[3];
  const float* out_b = (const float*)d_in[4];
  float* out = (float*)d_out;

  unsigned short* xb  = (unsigned short*)d_ws;                 // 8 MB  x bf16 [4096][1024]
  unsigned short* qwb = xb  + (size_t)4096 * 1024;             // 6 MB  qkv_w bf16
  unsigned short* owb = qwb + (size_t)3072 * 1024;             // 2 MB  out_w bf16
  unsigned short* Qb  = owb + (size_t)1024 * 1024;             // 8 MB  Q*C2 [32][2048][64]
  unsigned short* Kb  = Qb  + (size_t)32 * 2048 * 64;          // 8 MB  K [32][2048][64]
  unsigned short* Vb  = Kb  + (size_t)32 * 2048 * 64;          // 8 MB  V^T [32][64][2048]
  unsigned short* vb  = Vb  + (size_t)32 * 2048 * 64;          // 8 MB  vals bf16

  cvt_all<<<8192, 256, 0, stream>>>(x, qkv_w, out_w, xb, qwb, owb);
  gemm_bt<0, 128><<<dim3(32, 24), 256, 0, stream>>>(xb, qwb, qkv_b, nullptr, Qb, Kb, Vb,
                                                    4096, 3072, 1024);
  attn_fwd<<<256, 512, 0, stream>>>(Qb, Kb, Vb, vb);
  gemm_bt<1, 64><<<dim3(64, 8), 256, 0, stream>>>(vb, owb, out_b, out, nullptr, nullptr, nullptr,
                                                  4096, 1024, 1024);
}

// Round 10
// 107.204 us; speedup vs baseline: 1.4767x; 1.0907x over previous
//
#include <hip/hip_runtime.h>

// ---------- types ----------
using bh8    = __attribute__((ext_vector_type(8)))  short;          // 8 bf16 (4 VGPR)
using f32x4v = __attribute__((ext_vector_type(4)))  float;
using f32x16 = __attribute__((ext_vector_type(16))) float;
using u32x4  = __attribute__((ext_vector_type(4)))  unsigned int;
using us4    = __attribute__((ext_vector_type(4)))  unsigned short;

#define AS1 __attribute__((address_space(1)))
#define AS3 __attribute__((address_space(3)))

#define B_  2
#define S_  2048
#define D_  1024
#define H_  16
#define HD_ 64
#define C2A 0.0360673760222241f   // 0.2/sqrt(64) * log2(e), folded into Q

__device__ __forceinline__ unsigned short f2bf(float f) {
  unsigned u = __builtin_bit_cast(unsigned, f);
  return (unsigned short)((u + 0x7fffu + ((u >> 16) & 1u)) >> 16);   // RNE
}
__device__ __forceinline__ int swz8(int r) { return (r ^ (r >> 3)) & 7; }

// ---------- fused f32 -> bf16 convert (x, qkv_w, out_w in one launch) ----------
__global__ __launch_bounds__(256) void cvt_all(const float* __restrict__ x,
                                               const float* __restrict__ qw,
                                               const float* __restrict__ ow,
                                               unsigned short* __restrict__ xb,
                                               unsigned short* __restrict__ qwb,
                                               unsigned short* __restrict__ owb) {
  int i = blockIdx.x * 256 + threadIdx.x;     // vec4 index over 8M floats
  const float* src; unsigned short* dst; int off;
  if (i < 1048576)      { src = x;  dst = xb;  off = i; }
  else if (i < 1835008) { src = qw; dst = qwb; off = i - 1048576; }
  else                  { src = ow; dst = owb; off = i - 1835008; }
  f32x4v v = reinterpret_cast<const f32x4v*>(src)[off];
  us4 o;
  o[0] = f2bf(v[0]); o[1] = f2bf(v[1]); o[2] = f2bf(v[2]); o[3] = f2bf(v[3]);
  reinterpret_cast<us4*>(dst)[off] = o;
}

// ---------- GEMM: C[m,e] = sum_k A[m,k]*B[e,k] (+bias) ----------
// MODE 0: scatter bf16: Q (scaled by C2A) [bh][s][64], K [bh][s][64], V^T [bh][d][S]
// MODE 1: f32 out C[m*N+e] (+bias)
// BM: 128 (waves 2x2, acc[4][4]) or 64 (waves 1x4, acc[4][2])
// GX = gridDim.x, NW = total blocks (both %8 == 0) for bijective XCD swizzle (T1)
template <int MODE, int BM, int GX, int NW>
__global__ __launch_bounds__(256) void gemm_bt(const unsigned short* __restrict__ A,
                                               const unsigned short* __restrict__ Bw,
                                               const float* __restrict__ bias,
                                               float* __restrict__ Cf,
                                               unsigned short* __restrict__ Qo,
                                               unsigned short* __restrict__ Ko,
                                               unsigned short* __restrict__ Vo,
                                               int M, int N, int K) {
  constexpr int NIW = (BM == 128) ? 4 : 2;     // n-frags per wave
  constexpr int NA  = BM / 32;                 // A-staging issues: 256thr*16B = 4KB = 32 rows
  __shared__ __align__(16) short As[BM * 64];
  __shared__ __align__(16) short Bs[128 * 64];
  const int tid = threadIdx.x;
  const int w = tid >> 6, l = tid & 63;
  const int lr = l & 15, lg = l >> 4;
  // XCD swizzle: bijective since NW % 8 == 0
  const int lin = blockIdx.y * GX + blockIdx.x;
  const int sw  = (lin & 7) * (NW / 8) + (lin >> 3);
  const int m0 = (sw % GX) * BM, n0 = (sw / GX) * 128;
  const int wm = (BM == 128) ? (w >> 1) * 64 : 0;
  const int wn = (BM == 128) ? (w & 1) * 64 : w * 32;

  f32x4v acc[4][NIW];
#pragma unroll
  for (int a = 0; a < 4; a++)
#pragma unroll
    for (int b = 0; b < NIW; b++)
#pragma unroll
      for (int r = 0; r < 4; r++) acc[a][b][r] = 0.f;

#pragma unroll 1
  for (int k0 = 0; k0 < K; k0 += 64) {
    __syncthreads();
#pragma unroll
    for (int n = 0; n < NA; n++) {
      int idx = n * 256 + tid;
      int row = idx >> 3, p = idx & 7;
      int c = p ^ swz8(row);
      const unsigned short* srcA = A + (size_t)(m0 + row) * K + k0 + c * 8;
      __builtin_amdgcn_global_load_lds((const AS1 void*)srcA,
          (AS3 void*)((char*)As + (n * 256 + w * 64) * 16), 16, 0, 0);
    }
#pragma unroll
    for (int n = 0; n < 4; n++) {
      int idx = n * 256 + tid;
      int row = idx >> 3, p = idx & 7;
      int c = p ^ swz8(row);
      const unsigned short* srcB = Bw + (size_t)(n0 + row) * K + k0 + c * 8;
      __builtin_amdgcn_global_load_lds((const AS1 void*)srcB,
          (AS3 void*)((char*)Bs + (n * 256 + w * 64) * 16), 16, 0, 0);
    }
    __syncthreads();
#pragma unroll
    for (int kk = 0; kk < 2; kk++) {
      bh8 af[4], bf[NIW];
#pragma unroll
      for (int mi = 0; mi < 4; mi++) {
        int row = wm + mi * 16 + lr;
        int slot = (4 * kk + lg) ^ swz8(row);
        af[mi] = *(const bh8*)((const char*)As + row * 128 + slot * 16);
      }
#pragma unroll
      for (int ni = 0; ni < NIW; ni++) {
        int row = wn + ni * 16 + lr;
        int slot = (4 * kk + lg) ^ swz8(row);
        bf[ni] = *(const bh8*)((const char*)Bs + row * 128 + slot * 16);
      }
#pragma unroll
      for (int mi = 0; mi < 4; mi++)
#pragma unroll
        for (int ni = 0; ni < NIW; ni++)
          acc[mi][ni] = __builtin_amdgcn_mfma_f32_16x16x32_bf16(af[mi], bf[ni], acc[mi][ni], 0, 0, 0);
    }
  }

  // D layout (16x16): col=e=lane&15, row=m=(lane>>4)*4+r  [m89]
  if (MODE == 1) {
#pragma unroll
    for (int ni = 0; ni < NIW; ni++) {
      int e = n0 + wn + ni * 16 + lr;
      float bv = bias[e];
#pragma unroll
      for (int mi = 0; mi < 4; mi++) {
        int mbase = m0 + wm + mi * 16 + lg * 4;
#pragma unroll
        for (int r = 0; r < 4; r++)
          Cf[(size_t)(mbase + r) * N + e] = acc[mi][ni][r] + bv;
      }
    }
  } else {
#pragma unroll
    for (int ni = 0; ni < NIW; ni++) {
      int e = n0 + wn + ni * 16 + lr;
      int hh = e / 192;
      int rr = e - hh * 192;
      int tsel = rr >> 6, d = rr & 63;
      float bv = bias[e];
#pragma unroll
      for (int mi = 0; mi < 4; mi++) {
        int mbase = m0 + wm + mi * 16 + lg * 4;
#pragma unroll
        for (int r = 0; r < 4; r++) {
          int m = mbase + r;
          int b = m >> 11, s = m & 2047;
          float val = acc[mi][ni][r] + bv;
          size_t bh = (size_t)(b * H_ + hh);
          if (tsel == 0)      Qo[(bh * S_ + s) * HD_ + d] = f2bf(val * C2A);
          else if (tsel == 1) Ko[(bh * S_ + s) * HD_ + d] = f2bf(val);
          else                Vo[(bh * HD_ + d) * S_ + s] = f2bf(val);   // V^T
        }
      }
    }
  }
}

// ---------- fused attention ----------
// grid 256 (XCD-swizzled), 512 thr = 8 waves, each wave owns 32 q-rows and
// iterates ALL t. 128 t-rows per barrier (two 64-t tiles staged per iter,
// 4 global_load_lds/thread, 64KB dbuf LDS): halves sync/drain count vs R9.
// Per-tile math byte-identical to R9; t-ascending order -> bit-identical out.
__global__ __launch_bounds__(512) void attn_fwd(const unsigned short* __restrict__ Qt,
                                                const unsigned short* __restrict__ Kt,
                                                const unsigned short* __restrict__ VT,
                                                unsigned short* __restrict__ vals) {
  __shared__ __align__(16) short Ks[2 * 2 * 64 * 64];   // [buf][tile][64][64] 32KB
  __shared__ __align__(16) short Vs[2 * 2 * 64 * 64];   // 32KB
  const int tid = threadIdx.x, w = tid >> 6, l = tid & 63;
  const int lq = l & 31, h = l >> 5;
  // XCD swizzle: all 8 q-blocks of a (b,h) land on one XCD (same lin%8)
  const int lin = blockIdx.x;
  const int uu_ = lin >> 3;
  const int bh = (lin & 7) + 8 * (uu_ & 3);
  const int q0 = (uu_ >> 2) * 256 + w * 32;
  const unsigned short* Qp = Qt + (size_t)bh * (S_ * HD_);
  const unsigned short* Kp = Kt + (size_t)bh * (S_ * HD_);
  const unsigned short* Vp = VT + (size_t)bh * (HD_ * S_);

  bh8 qf[4];  // B-frags: col=q=lane&31, k=d=(lane>>5)*8+j
#pragma unroll
  for (int kf = 0; kf < 4; kf++)
    qf[kf] = *(const bh8*)(Qp + (size_t)(q0 + lq) * HD_ + kf * 16 + h * 8);

  // persistent zero C-operand
  f32x16 KZ;
#pragma unroll
  for (int r = 0; r < 16; r++) KZ[r] = 0.f;
  bh8 ones;
#pragma unroll
  for (int j = 0; j < 8; j++) ones[j] = (short)0x3F80;

  f32x16 O[2], Ol;
  O[0] = KZ; O[1] = KZ; Ol = KZ;

  // per-thread staging addresses (512 threads cover one 64x64 tile per issue)
  const int row0 = tid >> 3, cc = (tid & 7) ^ swz8(row0);
  const unsigned short* kp0 = Kp + row0 * HD_ + cc * 8;
  const unsigned short* vp0 = Vp + (size_t)row0 * S_ + cc * 8;
  char* dK = (char*)Ks + w * 1024;
  char* dV = (char*)Vs + w * 1024;

  // i indexes 128-t super-tiles; tiles at t = 128i and 128i+64
  auto stage = [&](int i, int buf) {
    const unsigned short* kB = kp0 + (size_t)i * 8192;   // 128 rows * 64 elems
    const unsigned short* vB = vp0 + (size_t)i * 128;    // V^T: +128 t-elems
    __builtin_amdgcn_global_load_lds((const AS1 void*)kB,
                                     (AS3 void*)(dK + buf * 16384), 16, 0, 0);
    __builtin_amdgcn_global_load_lds((const AS1 void*)(kB + 4096),
                                     (AS3 void*)(dK + buf * 16384 + 8192), 16, 0, 0);
    __builtin_amdgcn_global_load_lds((const AS1 void*)vB,
                                     (AS3 void*)(dV + buf * 16384), 16, 0, 0);
    __builtin_amdgcn_global_load_lds((const AS1 void*)(vB + 64),
                                     (AS3 void*)(dV + buf * 16384 + 8192), 16, 0, 0);
  };

  // LDS read byte-offsets within a 64x64 tile (loop-invariant)
  int ko0[4], ko1[4], vo0[4], vo1[4];
#pragma unroll
  for (int kf = 0; kf < 4; kf++) {
    int r0 = lq, r1 = 32 + lq;
    ko0[kf] = r0 * 128 + (((2 * kf + h) ^ swz8(r0)) << 4);
    ko1[kf] = r1 * 128 + (((2 * kf + h) ^ swz8(r1)) << 4);
  }
#pragma unroll
  for (int c = 0; c < 2; c++)
#pragma unroll
    for (int ni = 0; ni < 2; ni++) {
      int d = ni * 32 + lq;
      vo0[c * 2 + ni] = d * 128 + (((2 * c + h) ^ swz8(d)) << 4);
      vo1[c * 2 + ni] = d * 128 + (((4 + 2 * c + h) ^ swz8(d)) << 4);
    }

  stage(0, 0);
#pragma unroll 1
  for (int i = 0; i < 16; i++) {
    const int cur = i & 1;
    asm volatile("s_waitcnt vmcnt(0)" ::: "memory");   // my tile-i staging done
    __builtin_amdgcn_s_barrier();                      // everyone staged; prev-buf readers done
    if (i < 15) stage(i + 1, cur ^ 1);                 // prefetch flies under compute
#pragma unroll
    for (int tt = 0; tt < 2; tt++) {
      const char* Kc = (const char*)Ks + cur * 16384 + tt * 8192;
      const char* Vc = (const char*)Vs + cur * 16384 + tt * 8192;

      // ---- QK^T, both 32-t sub-tiles ----
      f32x16 sa, sb;
      __builtin_amdgcn_s_setprio(1);
      {
        bh8 k0 = *(const bh8*)(Kc + ko0[0]);
        bh8 k1 = *(const bh8*)(Kc + ko1[0]);
        sa = __builtin_amdgcn_mfma_f32_32x32x16_bf16(k0, qf[0], KZ, 0, 0, 0);
        sb = __builtin_amdgcn_mfma_f32_32x32x16_bf16(k1, qf[0], KZ, 0, 0, 0);
      }
#pragma unroll
      for (int kf = 1; kf < 4; kf++) {
        bh8 k0 = *(const bh8*)(Kc + ko0[kf]);
        bh8 k1 = *(const bh8*)(Kc + ko1[kf]);
        sa = __builtin_amdgcn_mfma_f32_32x32x16_bf16(k0, qf[kf], sa, 0, 0, 0);
        sb = __builtin_amdgcn_mfma_f32_32x32x16_bf16(k1, qf[kf], sb, 0, 0, 0);
      }
      __builtin_amdgcn_s_setprio(0);

      // ---- softmax numerators, chain a then chain b ----
      float pa_[16], pb_[16];
#pragma unroll
      for (int r = 0; r < 16; r++)
        asm("v_exp_f32 %0, %1" : "=v"(pa_[r]) : "v"(sa[r]));
      unsigned wa0[4], wa1[4];
#pragma unroll
      for (int g = 0; g < 4; g++) {
        asm("v_cvt_pk_bf16_f32 %0, %1, %2" : "=v"(wa0[g]) : "v"(pa_[4 * g]), "v"(pa_[4 * g + 1]));
        asm("v_cvt_pk_bf16_f32 %0, %1, %2" : "=v"(wa1[g]) : "v"(pa_[4 * g + 2]), "v"(pa_[4 * g + 3]));
      }
#pragma unroll
      for (int r = 0; r < 16; r++)
        asm("v_exp_f32 %0, %1" : "=v"(pb_[r]) : "v"(sb[r]));
      unsigned wb0[4], wb1[4];
#pragma unroll
      for (int g = 0; g < 4; g++) {
        asm("v_cvt_pk_bf16_f32 %0, %1, %2" : "=v"(wb0[g]) : "v"(pb_[4 * g]), "v"(pb_[4 * g + 1]));
        asm("v_cvt_pk_bf16_f32 %0, %1, %2" : "=v"(wb1[g]) : "v"(pb_[4 * g + 2]), "v"(pb_[4 * g + 3]));
      }

      // ---- rebuild PV A-frags via permlane32_swap (T12) ----
      bh8 paf[2], pbf[2];
#pragma unroll
      for (int c = 0; c < 2; c++) {
        unsigned x0 = wa0[2 * c], y0 = wa0[2 * c + 1];
        unsigned x1 = wa1[2 * c], y1 = wa1[2 * c + 1];
        asm("v_permlane32_swap_b32 %0, %1" : "+v"(x0), "+v"(y0));
        asm("v_permlane32_swap_b32 %0, %1" : "+v"(x1), "+v"(y1));
        u32x4 up; up[0] = x0; up[1] = x1; up[2] = y0; up[3] = y1;
        paf[c] = __builtin_bit_cast(bh8, up);
      }
#pragma unroll
      for (int c = 0; c < 2; c++) {
        unsigned x0 = wb0[2 * c], y0 = wb0[2 * c + 1];
        unsigned x1 = wb1[2 * c], y1 = wb1[2 * c + 1];
        asm("v_permlane32_swap_b32 %0, %1" : "+v"(x0), "+v"(y0));
        asm("v_permlane32_swap_b32 %0, %1" : "+v"(x1), "+v"(y1));
        u32x4 up; up[0] = x0; up[1] = x1; up[2] = y0; up[3] = y1;
        pbf[c] = __builtin_bit_cast(bh8, up);
      }

      // ---- PV + L, both chains ----
      __builtin_amdgcn_s_setprio(1);
#pragma unroll
      for (int c = 0; c < 2; c++) {
        bh8 vf0 = *(const bh8*)(Vc + vo0[c * 2 + 0]);
        bh8 vf1 = *(const bh8*)(Vc + vo0[c * 2 + 1]);
        O[0] = __builtin_amdgcn_mfma_f32_32x32x16_bf16(paf[c], vf0, O[0], 0, 0, 0);
        O[1] = __builtin_amdgcn_mfma_f32_32x32x16_bf16(paf[c], vf1, O[1], 0, 0, 0);
        Ol   = __builtin_amdgcn_mfma_f32_32x32x16_bf16(paf[c], ones, Ol, 0, 0, 0);
      }
#pragma unroll
      for (int c = 0; c < 2; c++) {
        bh8 vf0 = *(const bh8*)(Vc + vo1[c * 2 + 0]);
        bh8 vf1 = *(const bh8*)(Vc + vo1[c * 2 + 1]);
        O[0] = __builtin_amdgcn_mfma_f32_32x32x16_bf16(pbf[c], vf0, O[0], 0, 0, 0);
        O[1] = __builtin_amdgcn_mfma_f32_32x32x16_bf16(pbf[c], vf1, O[1], 0, 0, 0);
        Ol   = __builtin_amdgcn_mfma_f32_32x32x16_bf16(pbf[c], ones, Ol, 0, 0, 0);
      }
      __builtin_amdgcn_s_setprio(0);
    }
  }

  // denominators already in Ol[r] = L[q_r] (replicated across lanes)
  float rl[16];
#pragma unroll
  for (int r = 0; r < 16; r++) rl[r] = __builtin_amdgcn_rcpf(Ol[r]);

  const int b = bh >> 4, hh = bh & 15;
#pragma unroll
  for (int ni = 0; ni < 2; ni++) {
    int d = ni * 32 + lq;
#pragma unroll
    for (int r = 0; r < 16; r++) {
      float vvv = O[ni][r] * rl[r];
      int qg = q0 + 4 * h + 8 * (r >> 2) + (r & 3);
      vals[((size_t)(b * S_ + qg)) * D_ + hh * HD_ + d] = f2bf(vvv);
    }
  }
}

// ---------- launch ----------
extern "C" void kernel_launch(void* const* d_in, const int* in_sizes, int n_in,
                              void* d_out, int out_size, void* d_ws, size_t ws_size,
                              hipStream_t stream) {
  const float* x     = (const float*)d_in[0];
  const float* qkv_w = (const float*)d_in[1];
  const float* qkv_b = (const float*)d_in[2];
  const float* out_w = (const float*)d_in[3];
  const float* out_b = (const float*)d_in[4];
  float* out = (float*)d_out;

  unsigned short* xb  = (unsigned short*)d_ws;                 // 8 MB  x bf16 [4096][1024]
  unsigned short* qwb = xb  + (size_t)4096 * 1024;             // 6 MB  qkv_w bf16
  unsigned short* owb = qwb + (size_t)3072 * 1024;             // 2 MB  out_w bf16
  unsigned short* Qb  = owb + (size_t)1024 * 1024;             // 8 MB  Q*C2 [32][2048][64]
  unsigned short* Kb  = Qb  + (size_t)32 * 2048 * 64;          // 8 MB  K [32][2048][64]
  unsigned short* Vb  = Kb  + (size_t)32 * 2048 * 64;          // 8 MB  V^T [32][64][2048]
  unsigned short* vb  = Vb  + (size_t)32 * 2048 * 64;          // 8 MB  vals bf16

  cvt_all<<<8192, 256, 0, stream>>>(x, qkv_w, out_w, xb, qwb, owb);
  gemm_bt<0, 128, 32, 768><<<dim3(32, 24), 256, 0, stream>>>(xb, qwb, qkv_b, nullptr, Qb, Kb, Vb,
                                                             4096, 3072, 1024);
  attn_fwd<<<256, 512, 0, stream>>>(Qb, Kb, Vb, vb);
  gemm_bt<1, 64, 64, 512><<<dim3(64, 8), 256, 0, stream>>>(vb, owb, out_b, out, nullptr, nullptr, nullptr,
                                                           4096, 1024, 1024);
}